// Round 5
// baseline (2062.054 us; speedup 1.0000x reference)
//
#include <hip/hip_runtime.h>

typedef short short8 __attribute__((ext_vector_type(8)));
typedef float f32x4 __attribute__((ext_vector_type(4)));
typedef float f32x16 __attribute__((ext_vector_type(16)));

#define NWIN 2304
#define SMEM_BYTES 117248

static __device__ __forceinline__ unsigned short f2bf(float f) {
  unsigned int u = __float_as_uint(f);
  u += 0x7FFFu + ((u >> 16) & 1u);   // RNE
  return (unsigned short)(u >> 16);
}
static __device__ __forceinline__ float bf2f(unsigned short s) {
  return __uint_as_float(((unsigned int)s) << 16);
}
static __device__ __forceinline__ f32x4 mfma16(short8 a, short8 b, f32x4 c) {
  return __builtin_amdgcn_mfma_f32_16x16x32_bf16(a, b, c, 0, 0, 0);
}
static __device__ __forceinline__ f32x16 mfma32(short8 a, short8 b, f32x16 c) {
  return __builtin_amdgcn_mfma_f32_32x32x16_bf16(a, b, c, 0, 0, 0);
}
static __device__ __forceinline__ short8 lds8(const unsigned short* p) {
  return *reinterpret_cast<const short8*>(p);
}
// XOR swizzles: 16B granule, spread by low row bits (balanced banks for b128 reads)
static __device__ __forceinline__ int swzT(int r, int c) {   // [64][512]
  return r * 512 + ((((c >> 3) ^ (r & 7)) << 3) | (c & 7));
}
static __device__ __forceinline__ int swz128(int r, int c) { // [64][128]
  return r * 128 + ((((c >> 3) ^ (r & 7)) << 3) | (c & 7));
}
static __device__ __forceinline__ int swzV(int r, int c) {   // [128][64]
  return r * 64 + ((((c >> 3) ^ (r & 7)) << 3) | (c & 7));
}

// ---- weight prep: in[K][N] f32  ->  out[N][K] bf16 ----
__global__ void transpose_cvt_kernel(const float* __restrict__ in,
                                     unsigned short* __restrict__ out,
                                     int K, int N) {
  __shared__ float tile[32][33];
  int bn = blockIdx.x * 32, bk = blockIdx.y * 32;
  int tx = threadIdx.x & 31, ty = threadIdx.x >> 5;  // 256 thr: 32 x 8
#pragma unroll
  for (int r = 0; r < 32; r += 8)
    tile[ty + r][tx] = in[(size_t)(bk + ty + r) * N + bn + tx];
  __syncthreads();
#pragma unroll
  for (int r = 0; r < 32; r += 8)
    out[(size_t)(bn + ty + r) * K + bk + tx] = f2bf(tile[tx][ty + r]);
}

__global__ __launch_bounds__(512, 2)
void swin_fused(const float* __restrict__ x,
                const unsigned short* __restrict__ WqkvT,  // [1536][512] bf16
                const float* __restrict__ bqkv,
                const unsigned short* __restrict__ WoT,    // [512][512]
                const float* __restrict__ bo,
                const float* __restrict__ g1, const float* __restrict__ beta1,
                const unsigned short* __restrict__ W1T,    // [512][512]
                const float* __restrict__ bf1,
                const unsigned short* __restrict__ W2T,    // [512][512]
                const float* __restrict__ bf2,
                const float* __restrict__ g2, const float* __restrict__ beta2,
                float* __restrict__ out) {
  extern __shared__ unsigned char smem[];
  unsigned short* sTm  = (unsigned short*)smem;              // [64][512] swz, 64KB
  unsigned short* sQm  = (unsigned short*)(smem + 65536);    // [64][128] swz: Q->P->O
  unsigned short* sKm  = (unsigned short*)(smem + 81920);    // [64][128] swz: K / hidden
  unsigned short* sVtm = (unsigned short*)(smem + 98304);    // [128][64] swz: V^T
  unsigned short* sHm  = sKm;
  float* sSum  = (float*)(smem + 114688);                    // [4][64]
  float* sSq   = (float*)(smem + 115712);                    // [4][64]
  float* sMean = (float*)(smem + 116736);                    // [64]
  float* sRstd = (float*)(smem + 116992);                    // [64]

  const int tid = threadIdx.x;
  const int wvid = tid >> 6, lane = tid & 63;
  const int l16 = lane & 15, lg = lane >> 4;
  const int l32 = lane & 31, kh = lane >> 5, kh8 = kh << 3;

  // XCD swizzle
  const int wid = (blockIdx.x & 7) * 288 + (blockIdx.x >> 3);
  const int b = wid / 144, rem = wid % 144;
  const int h0 = (rem / 12) * 8, w0 = (rem % 12) * 8;
  const float* xb = x + (size_t)b * 512 * 9216 + (size_t)h0 * 96 + w0;
  float* ob = out + (size_t)b * 512 * 9216 + (size_t)h0 * 96 + w0;

  // wave roles
  const int rt = wvid & 1;          // 32-row tile (A / OP / F1 / F2 / LN)
  const int g4 = wvid >> 1;         // 32-col group within 128 (A / F1)
  const int ctg = wvid >> 1;        // 128-col group within 512 (OP / F2 / LN)
  const int hh = wvid >> 2;         // head within pair (S / PV)
  const int mt4 = wvid & 3;         // 16-row tile (S / PV)
  const int c128 = g4 * 32 + l32;   // col within 128 (A / F1)
  const int arow = rt * 32 + l32;   // A-frag row (32x32 MFMA)

  // ---- Phase 0: gather window -> sT (bf16, swizzled), float4 reads ----
#pragma unroll
  for (int it = 0; it < 16; ++it) {
    int gid = it * 512 + tid;                 // gid = c*16 + hr*2 + wq
    int c = gid >> 4, hr = (gid >> 1) & 7, wq = gid & 1;
    float4 v = *reinterpret_cast<const float4*>(xb + (size_t)c * 9216 + hr * 96 + wq * 4);
    int tok = hr * 8 + wq * 4;
    sTm[swzT(tok + 0, c)] = f2bf(v.x);
    sTm[swzT(tok + 1, c)] = f2bf(v.y);
    sTm[swzT(tok + 2, c)] = f2bf(v.z);
    sTm[swzT(tok + 3, c)] = f2bf(v.w);
  }
  __syncthreads();

  f32x16 Yacc[4] = {};  // persistent o-proj accumulator: 4 col tiles of 32x32

  for (int hp = 0; hp < 4; ++hp) {   // head pairs
    // ---- Phase A: q,k,v (wave: rows rt*32..+32, qkv cols c128; 32x32 MFMA) ----
    {
      const unsigned short* bq = WqkvT + (size_t)(hp * 128 + c128) * 512;
      const unsigned short* bk = bq + (size_t)512 * 512;
      const unsigned short* bv = bq + (size_t)1024 * 512;
      f32x16 aq = {}, ak = {}, av = {};
      short8 qw[4], kw[4], vw[4];
#pragma unroll
      for (int p = 0; p < 4; ++p) {
        int ko = p * 16 + kh8;
        qw[p] = *(const short8*)(bq + ko);
        kw[p] = *(const short8*)(bk + ko);
        vw[p] = *(const short8*)(bv + ko);
      }
#pragma unroll
      for (int ks = 0; ks < 32; ++ks) {
        short8 cq = qw[ks & 3], ck = kw[ks & 3], cv = vw[ks & 3];
        if (ks < 28) {
          int ko = (ks + 4) * 16 + kh8;
          qw[ks & 3] = *(const short8*)(bq + ko);
          kw[ks & 3] = *(const short8*)(bk + ko);
          vw[ks & 3] = *(const short8*)(bv + ko);
        }
        short8 a = lds8(sTm + swzT(arow, ks * 16 + kh8));
        aq = mfma32(a, cq, aq);
        ak = mfma32(a, ck, ak);
        av = mfma32(a, cv, av);
      }
      const float bqv = bqkv[hp * 128 + c128];
      const float bkv = bqkv[512 + hp * 128 + c128];
      const float bvv = bqkv[1024 + hp * 128 + c128];
#pragma unroll
      for (int reg = 0; reg < 16; ++reg) {
        int row = rt * 32 + (reg & 3) + ((reg & 12) << 1) + (kh << 2);
        sQm[swz128(row, c128)] = f2bf((aq[reg] + bqv) * 0.125f);
        sKm[swz128(row, c128)] = f2bf(ak[reg] + bkv);
      }
#pragma unroll
      for (int q = 0; q < 4; ++q) {
        int t0 = rt * 32 + q * 8 + (kh << 2);
        ushort4 pk;
        pk.x = f2bf(av[4 * q + 0] + bvv);
        pk.y = f2bf(av[4 * q + 1] + bvv);
        pk.z = f2bf(av[4 * q + 2] + bvv);
        pk.w = f2bf(av[4 * q + 3] + bvv);
        *reinterpret_cast<ushort4*>(sVtm + swzV(c128, t0)) = pk;
      }
    }
    __syncthreads();

    // ---- Phase S: scores + wave-local softmax (16x16; wave: head hh, rows mt4*16..) ----
    {
      f32x4 sc[4] = {};
#pragma unroll
      for (int ks = 0; ks < 2; ++ks) {
        int kbase = hh * 64 + ks * 32 + lg * 8;
        short8 a  = lds8(sQm + swz128(mt4 * 16 + l16, kbase));
        short8 b0 = lds8(sKm + swz128(l16, kbase));
        short8 b1 = lds8(sKm + swz128(16 + l16, kbase));
        short8 b2 = lds8(sKm + swz128(32 + l16, kbase));
        short8 b3 = lds8(sKm + swz128(48 + l16, kbase));
        sc[0] = mfma16(a, b0, sc[0]);
        sc[1] = mfma16(a, b1, sc[1]);
        sc[2] = mfma16(a, b2, sc[2]);
        sc[3] = mfma16(a, b3, sc[3]);
      }
#pragma unroll
      for (int r = 0; r < 4; ++r) {
        float m = fmaxf(fmaxf(sc[0][r], sc[1][r]), fmaxf(sc[2][r], sc[3][r]));
        m = fmaxf(m, __shfl_xor(m, 1));
        m = fmaxf(m, __shfl_xor(m, 2));
        m = fmaxf(m, __shfl_xor(m, 4));
        m = fmaxf(m, __shfl_xor(m, 8));
        float e0 = __expf(sc[0][r] - m), e1 = __expf(sc[1][r] - m);
        float e2 = __expf(sc[2][r] - m), e3 = __expf(sc[3][r] - m);
        float s = e0 + e1 + e2 + e3;
        s += __shfl_xor(s, 1);
        s += __shfl_xor(s, 2);
        s += __shfl_xor(s, 4);
        s += __shfl_xor(s, 8);
        float inv = 1.0f / s;
        int row = mt4 * 16 + lg * 4 + r;
        sQm[swz128(row, hh * 64 + l16)]      = f2bf(e0 * inv);   // P over Q (own rows/cols)
        sQm[swz128(row, hh * 64 + 16 + l16)] = f2bf(e1 * inv);
        sQm[swz128(row, hh * 64 + 32 + l16)] = f2bf(e2 * inv);
        sQm[swz128(row, hh * 64 + 48 + l16)] = f2bf(e3 * inv);
      }
    }
    // no barrier: P produced and consumed by same wave

    // ---- Phase PV: O = P @ V (write O over P, own region) ----
    {
      f32x4 ov[4] = {};
#pragma unroll
      for (int ks = 0; ks < 2; ++ks) {
        int kbase = ks * 32 + lg * 8;
        short8 a  = lds8(sQm + swz128(mt4 * 16 + l16, hh * 64 + kbase));
        short8 b0 = lds8(sVtm + swzV(hh * 64 + l16, kbase));
        short8 b1 = lds8(sVtm + swzV(hh * 64 + 16 + l16, kbase));
        short8 b2 = lds8(sVtm + swzV(hh * 64 + 32 + l16, kbase));
        short8 b3 = lds8(sVtm + swzV(hh * 64 + 48 + l16, kbase));
        ov[0] = mfma16(a, b0, ov[0]);
        ov[1] = mfma16(a, b1, ov[1]);
        ov[2] = mfma16(a, b2, ov[2]);
        ov[3] = mfma16(a, b3, ov[3]);
      }
#pragma unroll
      for (int r = 0; r < 4; ++r) {
        int row = mt4 * 16 + lg * 4 + r;
        sQm[swz128(row, hh * 64 + l16)]      = f2bf(ov[0][r]);
        sQm[swz128(row, hh * 64 + 16 + l16)] = f2bf(ov[1][r]);
        sQm[swz128(row, hh * 64 + 32 + l16)] = f2bf(ov[2][r]);
        sQm[swz128(row, hh * 64 + 48 + l16)] = f2bf(ov[3][r]);
      }
    }
    __syncthreads();

    // ---- Phase OP: Yacc += O(2 heads) @ Wo[hp*128.., ctg*128..+128] (32x32) ----
    {
      const unsigned short* wo[4];
#pragma unroll
      for (int ct = 0; ct < 4; ++ct)
        wo[ct] = WoT + (size_t)(ctg * 128 + ct * 32 + l32) * 512 + hp * 128;
      short8 wb[2][4];
#pragma unroll
      for (int p = 0; p < 2; ++p)
#pragma unroll
        for (int ct = 0; ct < 4; ++ct)
          wb[p][ct] = *(const short8*)(wo[ct] + p * 16 + kh8);
#pragma unroll
      for (int ks = 0; ks < 8; ++ks) {
        short8 a = lds8(sQm + swz128(rt * 32 + l32, ks * 16 + kh8));
#pragma unroll
        for (int ct = 0; ct < 4; ++ct) {
          short8 w = wb[ks & 1][ct];
          if (ks < 6) wb[ks & 1][ct] = *(const short8*)(wo[ct] + (ks + 2) * 16 + kh8);
          Yacc[ct] = mfma32(a, w, Yacc[ct]);
        }
      }
    }
    __syncthreads();  // next Phase A rewrites sQ/sK/sVt
  }

  // ---- Residual 1 + LayerNorm 1 -> x1 (overwrites sT) ----
  {
#pragma unroll
    for (int ct = 0; ct < 4; ++ct) {
      int col = ctg * 128 + ct * 32 + l32;
      float bv = bo[col];
#pragma unroll
      for (int reg = 0; reg < 16; ++reg) {
        int row = rt * 32 + (reg & 3) + ((reg & 12) << 1) + (kh << 2);
        Yacc[ct][reg] += bv + bf2f(sTm[swzT(row, col)]);
      }
    }
#pragma unroll
    for (int reg = 0; reg < 16; ++reg) {
      float s = Yacc[0][reg] + Yacc[1][reg] + Yacc[2][reg] + Yacc[3][reg];
      float q = Yacc[0][reg] * Yacc[0][reg] + Yacc[1][reg] * Yacc[1][reg] +
                Yacc[2][reg] * Yacc[2][reg] + Yacc[3][reg] * Yacc[3][reg];
      s += __shfl_xor(s, 1);  s += __shfl_xor(s, 2);
      s += __shfl_xor(s, 4);  s += __shfl_xor(s, 8);  s += __shfl_xor(s, 16);
      q += __shfl_xor(q, 1);  q += __shfl_xor(q, 2);
      q += __shfl_xor(q, 4);  q += __shfl_xor(q, 8);  q += __shfl_xor(q, 16);
      if (l32 == 0) {
        int row = rt * 32 + (reg & 3) + ((reg & 12) << 1) + (kh << 2);
        sSum[ctg * 64 + row] = s;
        sSq[ctg * 64 + row]  = q;
      }
    }
    __syncthreads();
    if (tid < 64) {
      float s = sSum[tid] + sSum[64 + tid] + sSum[128 + tid] + sSum[192 + tid];
      float q = sSq[tid] + sSq[64 + tid] + sSq[128 + tid] + sSq[192 + tid];
      float mean = s * (1.0f / 512.0f);
      float var = q * (1.0f / 512.0f) - mean * mean;
      sMean[tid] = mean;
      sRstd[tid] = rsqrtf(var + 1e-5f);
    }
    __syncthreads();
#pragma unroll
    for (int ct = 0; ct < 4; ++ct) {
      int col = ctg * 128 + ct * 32 + l32;
      float gv = g1[col], bv = beta1[col];
#pragma unroll
      for (int reg = 0; reg < 16; ++reg) {
        int row = rt * 32 + (reg & 3) + ((reg & 12) << 1) + (kh << 2);
        float xv = (Yacc[ct][reg] - sMean[row]) * sRstd[row] * gv + bv;
        sTm[swzT(row, col)] = f2bf(xv);
      }
    }
  }
  __syncthreads();

  // ---- FFN: 4 hidden chunks of 128 ----
  f32x16 Facc[4] = {};
  for (int hc = 0; hc < 4; ++hc) {
    // F1: u = relu(x1 @ W1 chunk) (32x32; wave: rows rt*32.., hidden col c128)
    {
      const int hcol = hc * 128 + c128;
      const unsigned short* w1p = W1T + (size_t)hcol * 512;
      f32x16 u = {};
      short8 wbuf[4];
#pragma unroll
      for (int p = 0; p < 4; ++p)
        wbuf[p] = *(const short8*)(w1p + p * 16 + kh8);
#pragma unroll
      for (int ks = 0; ks < 32; ++ks) {
        short8 cw = wbuf[ks & 3];
        if (ks < 28)
          wbuf[ks & 3] = *(const short8*)(w1p + (ks + 4) * 16 + kh8);
        short8 a = lds8(sTm + swzT(arow, ks * 16 + kh8));
        u = mfma32(a, cw, u);
      }
      float bv = bf1[hcol];
#pragma unroll
      for (int reg = 0; reg < 16; ++reg) {
        int row = rt * 32 + (reg & 3) + ((reg & 12) << 1) + (kh << 2);
        sHm[swz128(row, c128)] = f2bf(fmaxf(u[reg] + bv, 0.0f));
      }
    }
    __syncthreads();
    // F2: Facc += u @ W2[hc*128.., ctg*128..+128]
    {
      const unsigned short* w2[4];
#pragma unroll
      for (int ct = 0; ct < 4; ++ct)
        w2[ct] = W2T + (size_t)(ctg * 128 + ct * 32 + l32) * 512 + hc * 128;
      short8 wb[2][4];
#pragma unroll
      for (int p = 0; p < 2; ++p)
#pragma unroll
        for (int ct = 0; ct < 4; ++ct)
          wb[p][ct] = *(const short8*)(w2[ct] + p * 16 + kh8);
#pragma unroll
      for (int ks = 0; ks < 8; ++ks) {
        short8 a = lds8(sHm + swz128(rt * 32 + l32, ks * 16 + kh8));
#pragma unroll
        for (int ct = 0; ct < 4; ++ct) {
          short8 w = wb[ks & 1][ct];
          if (ks < 6) wb[ks & 1][ct] = *(const short8*)(w2[ct] + (ks + 2) * 16 + kh8);
          Facc[ct] = mfma32(a, w, Facc[ct]);
        }
      }
    }
    __syncthreads();  // sH reused next chunk
  }

  // ---- Residual 2 + LayerNorm 2 -> output ----
  {
#pragma unroll
    for (int ct = 0; ct < 4; ++ct) {
      int col = ctg * 128 + ct * 32 + l32;
      float bv = bf2[col];
#pragma unroll
      for (int reg = 0; reg < 16; ++reg) {
        int row = rt * 32 + (reg & 3) + ((reg & 12) << 1) + (kh << 2);
        Facc[ct][reg] += bv + bf2f(sTm[swzT(row, col)]);
      }
    }
#pragma unroll
    for (int reg = 0; reg < 16; ++reg) {
      float s = Facc[0][reg] + Facc[1][reg] + Facc[2][reg] + Facc[3][reg];
      float q = Facc[0][reg] * Facc[0][reg] + Facc[1][reg] * Facc[1][reg] +
                Facc[2][reg] * Facc[2][reg] + Facc[3][reg] * Facc[3][reg];
      s += __shfl_xor(s, 1);  s += __shfl_xor(s, 2);
      s += __shfl_xor(s, 4);  s += __shfl_xor(s, 8);  s += __shfl_xor(s, 16);
      q += __shfl_xor(q, 1);  q += __shfl_xor(q, 2);
      q += __shfl_xor(q, 4);  q += __shfl_xor(q, 8);  q += __shfl_xor(q, 16);
      if (l32 == 0) {
        int row = rt * 32 + (reg & 3) + ((reg & 12) << 1) + (kh << 2);
        sSum[ctg * 64 + row] = s;
        sSq[ctg * 64 + row]  = q;
      }
    }
    __syncthreads();
    if (tid < 64) {
      float s = sSum[tid] + sSum[64 + tid] + sSum[128 + tid] + sSum[192 + tid];
      float q = sSq[tid] + sSq[64 + tid] + sSq[128 + tid] + sSq[192 + tid];
      float mean = s * (1.0f / 512.0f);
      float var = q * (1.0f / 512.0f) - mean * mean;
      sMean[tid] = mean;
      sRstd[tid] = rsqrtf(var + 1e-5f);
    }
    __syncthreads();
#pragma unroll
    for (int ct = 0; ct < 4; ++ct) {
      int col = ctg * 128 + ct * 32 + l32;
      float gv = g2[col], bv = beta2[col];
      float* op = ob + (size_t)col * 9216;
#pragma unroll
      for (int q4 = 0; q4 < 4; ++q4) {
        int t0 = rt * 32 + q4 * 8 + (kh << 2);
        float4 o4;
        o4.x = (Facc[ct][4 * q4 + 0] - sMean[t0 + 0]) * sRstd[t0 + 0] * gv + bv;
        o4.y = (Facc[ct][4 * q4 + 1] - sMean[t0 + 1]) * sRstd[t0 + 1] * gv + bv;
        o4.z = (Facc[ct][4 * q4 + 2] - sMean[t0 + 2]) * sRstd[t0 + 2] * gv + bv;
        o4.w = (Facc[ct][4 * q4 + 3] - sMean[t0 + 3]) * sRstd[t0 + 3] * gv + bv;
        *reinterpret_cast<float4*>(op + (t0 >> 3) * 96 + (t0 & 7)) = o4;
      }
    }
  }
}

extern "C" void kernel_launch(void* const* d_in, const int* in_sizes, int n_in,
                              void* d_out, int out_size, void* d_ws, size_t ws_size,
                              hipStream_t stream) {
  const float* x     = (const float*)d_in[0];
  const float* Wqkv  = (const float*)d_in[1];
  const float* bqkv  = (const float*)d_in[2];
  const float* Wo    = (const float*)d_in[3];
  const float* bo    = (const float*)d_in[4];
  const float* g1    = (const float*)d_in[5];
  const float* beta1 = (const float*)d_in[6];
  const float* W1    = (const float*)d_in[7];
  const float* bf1   = (const float*)d_in[8];
  const float* W2    = (const float*)d_in[9];
  const float* bf2   = (const float*)d_in[10];
  const float* g2    = (const float*)d_in[11];
  const float* beta2 = (const float*)d_in[12];
  float* out = (float*)d_out;

  unsigned short* ws = (unsigned short*)d_ws;
  unsigned short* WqkvT = ws;                          // 1536*512
  unsigned short* WoT   = ws + (size_t)1536 * 512;
  unsigned short* W1T   = WoT + (size_t)512 * 512;
  unsigned short* W2T   = W1T + (size_t)512 * 512;

  transpose_cvt_kernel<<<dim3(48, 16), 256, 0, stream>>>(Wqkv, WqkvT, 512, 1536);
  transpose_cvt_kernel<<<dim3(16, 16), 256, 0, stream>>>(Wo, WoT, 512, 512);
  transpose_cvt_kernel<<<dim3(16, 16), 256, 0, stream>>>(W1, W1T, 512, 512);
  transpose_cvt_kernel<<<dim3(16, 16), 256, 0, stream>>>(W2, W2T, 512, 512);

  (void)hipFuncSetAttribute((const void*)swin_fused,
                            hipFuncAttributeMaxDynamicSharedMemorySize, SMEM_BYTES);
  swin_fused<<<NWIN, 512, SMEM_BYTES, stream>>>(x, WqkvT, bqkv, WoT, bo, g1, beta1,
                                                W1T, bf1, W2T, bf2, g2, beta2, out);
}

// Round 6
// 2052.274 us; speedup vs baseline: 1.0048x; 1.0048x over previous
//
#include <hip/hip_runtime.h>

typedef short short8 __attribute__((ext_vector_type(8)));
typedef float f32x4 __attribute__((ext_vector_type(4)));
typedef float f32x16 __attribute__((ext_vector_type(16)));

#define NWIN 2304
#define SMEM_BYTES 117248

static __device__ __forceinline__ unsigned short f2bf(float f) {
  unsigned int u = __float_as_uint(f);
  u += 0x7FFFu + ((u >> 16) & 1u);   // RNE
  return (unsigned short)(u >> 16);
}
static __device__ __forceinline__ float bf2f(unsigned short s) {
  return __uint_as_float(((unsigned int)s) << 16);
}
static __device__ __forceinline__ f32x4 mfma16(short8 a, short8 b, f32x4 c) {
  return __builtin_amdgcn_mfma_f32_16x16x32_bf16(a, b, c, 0, 0, 0);
}
static __device__ __forceinline__ f32x16 mfma32(short8 a, short8 b, f32x16 c) {
  return __builtin_amdgcn_mfma_f32_32x32x16_bf16(a, b, c, 0, 0, 0);
}
static __device__ __forceinline__ short8 lds8(const unsigned short* p) {
  return *reinterpret_cast<const short8*>(p);
}
// XOR swizzles: 16B granule, spread by low row bits (balanced banks for b128 reads)
static __device__ __forceinline__ int swzT(int r, int c) {   // [64][512]
  return r * 512 + ((((c >> 3) ^ (r & 7)) << 3) | (c & 7));
}
static __device__ __forceinline__ int swz128(int r, int c) { // [64][128]
  return r * 128 + ((((c >> 3) ^ (r & 7)) << 3) | (c & 7));
}
static __device__ __forceinline__ int swzV(int r, int c) {   // [128][64]
  return r * 64 + ((((c >> 3) ^ (r & 7)) << 3) | (c & 7));
}

// ---- weight prep: in[K][N] f32  ->  out[N][K] bf16 ----
__global__ void transpose_cvt_kernel(const float* __restrict__ in,
                                     unsigned short* __restrict__ out,
                                     int K, int N) {
  __shared__ float tile[32][33];
  int bn = blockIdx.x * 32, bk = blockIdx.y * 32;
  int tx = threadIdx.x & 31, ty = threadIdx.x >> 5;  // 256 thr: 32 x 8
#pragma unroll
  for (int r = 0; r < 32; r += 8)
    tile[ty + r][tx] = in[(size_t)(bk + ty + r) * N + bn + tx];
  __syncthreads();
#pragma unroll
  for (int r = 0; r < 32; r += 8)
    out[(size_t)(bn + ty + r) * K + bk + tx] = f2bf(tile[tx][ty + r]);
}

__global__ __launch_bounds__(512)
__attribute__((amdgpu_waves_per_eu(2, 2)))
void swin_fused(const float* __restrict__ x,
                const unsigned short* __restrict__ WqkvT,  // [1536][512] bf16
                const float* __restrict__ bqkv,
                const unsigned short* __restrict__ WoT,    // [512][512]
                const float* __restrict__ bo,
                const float* __restrict__ g1, const float* __restrict__ beta1,
                const unsigned short* __restrict__ W1T,    // [512][512]
                const float* __restrict__ bf1,
                const unsigned short* __restrict__ W2T,    // [512][512]
                const float* __restrict__ bf2,
                const float* __restrict__ g2, const float* __restrict__ beta2,
                float* __restrict__ out) {
  extern __shared__ unsigned char smem[];
  unsigned short* sTm  = (unsigned short*)smem;              // [64][512] swz, 64KB
  unsigned short* sQm  = (unsigned short*)(smem + 65536);    // [64][128] swz: Q->P->O
  unsigned short* sKm  = (unsigned short*)(smem + 81920);    // [64][128] swz: K / hidden
  unsigned short* sVtm = (unsigned short*)(smem + 98304);    // [128][64] swz: V^T
  unsigned short* sHm  = sKm;
  float* sSum  = (float*)(smem + 114688);                    // [4][64]
  float* sSq   = (float*)(smem + 115712);                    // [4][64]
  float* sMean = (float*)(smem + 116736);                    // [64]
  float* sRstd = (float*)(smem + 116992);                    // [64]

  const int tid = threadIdx.x;
  const int wvid = tid >> 6, lane = tid & 63;
  const int l16 = lane & 15, lg = lane >> 4;
  const int l32 = lane & 31, kh = lane >> 5, kh8 = kh << 3;

  // XCD swizzle
  const int wid = (blockIdx.x & 7) * 288 + (blockIdx.x >> 3);
  const int b = wid / 144, rem = wid % 144;
  const int h0 = (rem / 12) * 8, w0 = (rem % 12) * 8;
  const float* xb = x + (size_t)b * 512 * 9216 + (size_t)h0 * 96 + w0;
  float* ob = out + (size_t)b * 512 * 9216 + (size_t)h0 * 96 + w0;

  // wave roles
  const int rt = wvid & 1;          // 32-row tile (A / OP / F1 / F2 / LN)
  const int g4 = wvid >> 1;         // 32-col group within 128 (A / F1)
  const int ctg = wvid >> 1;        // 128-col group within 512 (OP / F2 / LN)
  const int hh = wvid >> 2;         // head within pair (S / PV)
  const int mt4 = wvid & 3;         // 16-row tile (S / PV)
  const int c128 = g4 * 32 + l32;   // col within 128 (A / F1)
  const int arow = rt * 32 + l32;   // A-frag row (32x32 MFMA)

  // ---- Phase 0: gather window -> sT (bf16, swizzled), float4 reads ----
#pragma unroll
  for (int it = 0; it < 16; ++it) {
    int gid = it * 512 + tid;                 // gid = c*16 + hr*2 + wq
    int c = gid >> 4, hr = (gid >> 1) & 7, wq = gid & 1;
    float4 v = *reinterpret_cast<const float4*>(xb + (size_t)c * 9216 + hr * 96 + wq * 4);
    int tok = hr * 8 + wq * 4;
    sTm[swzT(tok + 0, c)] = f2bf(v.x);
    sTm[swzT(tok + 1, c)] = f2bf(v.y);
    sTm[swzT(tok + 2, c)] = f2bf(v.z);
    sTm[swzT(tok + 3, c)] = f2bf(v.w);
  }
  __syncthreads();

  f32x16 Yacc[4] = {};  // persistent o-proj accumulator: 4 col tiles of 32x32

  for (int hp = 0; hp < 4; ++hp) {   // head pairs
    // ---- Phase A: q,k,v (wave: rows rt*32..+32, qkv cols c128; 32x32 MFMA) ----
    {
      const unsigned short* bq = WqkvT + (size_t)(hp * 128 + c128) * 512;
      const unsigned short* bk = bq + (size_t)512 * 512;
      const unsigned short* bv = bq + (size_t)1024 * 512;
      f32x16 aq = {}, ak = {}, av = {};
      short8 qw[4], kw[4], vw[4];
#pragma unroll
      for (int p = 0; p < 4; ++p) {
        int ko = p * 16 + kh8;
        qw[p] = *(const short8*)(bq + ko);
        kw[p] = *(const short8*)(bk + ko);
        vw[p] = *(const short8*)(bv + ko);
      }
#pragma unroll
      for (int ks = 0; ks < 32; ++ks) {
        short8 cq = qw[ks & 3], ck = kw[ks & 3], cv = vw[ks & 3];
        if (ks < 28) {
          int ko = (ks + 4) * 16 + kh8;
          qw[ks & 3] = *(const short8*)(bq + ko);
          kw[ks & 3] = *(const short8*)(bk + ko);
          vw[ks & 3] = *(const short8*)(bv + ko);
        }
        short8 a = lds8(sTm + swzT(arow, ks * 16 + kh8));
        aq = mfma32(a, cq, aq);
        ak = mfma32(a, ck, ak);
        av = mfma32(a, cv, av);
      }
      const float bqv = bqkv[hp * 128 + c128];
      const float bkv = bqkv[512 + hp * 128 + c128];
      const float bvv = bqkv[1024 + hp * 128 + c128];
#pragma unroll
      for (int reg = 0; reg < 16; ++reg) {
        int row = rt * 32 + (reg & 3) + ((reg & 12) << 1) + (kh << 2);
        sQm[swz128(row, c128)] = f2bf((aq[reg] + bqv) * 0.125f);
        sKm[swz128(row, c128)] = f2bf(ak[reg] + bkv);
      }
#pragma unroll
      for (int q = 0; q < 4; ++q) {
        int t0 = rt * 32 + q * 8 + (kh << 2);
        ushort4 pk;
        pk.x = f2bf(av[4 * q + 0] + bvv);
        pk.y = f2bf(av[4 * q + 1] + bvv);
        pk.z = f2bf(av[4 * q + 2] + bvv);
        pk.w = f2bf(av[4 * q + 3] + bvv);
        *reinterpret_cast<ushort4*>(sVtm + swzV(c128, t0)) = pk;
      }
    }
    __syncthreads();

    // ---- Phase S: scores + wave-local softmax (16x16; wave: head hh, rows mt4*16..) ----
    {
      f32x4 sc[4] = {};
#pragma unroll
      for (int ks = 0; ks < 2; ++ks) {
        int kbase = hh * 64 + ks * 32 + lg * 8;
        short8 a  = lds8(sQm + swz128(mt4 * 16 + l16, kbase));
        short8 b0 = lds8(sKm + swz128(l16, kbase));
        short8 b1 = lds8(sKm + swz128(16 + l16, kbase));
        short8 b2 = lds8(sKm + swz128(32 + l16, kbase));
        short8 b3 = lds8(sKm + swz128(48 + l16, kbase));
        sc[0] = mfma16(a, b0, sc[0]);
        sc[1] = mfma16(a, b1, sc[1]);
        sc[2] = mfma16(a, b2, sc[2]);
        sc[3] = mfma16(a, b3, sc[3]);
      }
#pragma unroll
      for (int r = 0; r < 4; ++r) {
        float m = fmaxf(fmaxf(sc[0][r], sc[1][r]), fmaxf(sc[2][r], sc[3][r]));
        m = fmaxf(m, __shfl_xor(m, 1));
        m = fmaxf(m, __shfl_xor(m, 2));
        m = fmaxf(m, __shfl_xor(m, 4));
        m = fmaxf(m, __shfl_xor(m, 8));
        float e0 = __expf(sc[0][r] - m), e1 = __expf(sc[1][r] - m);
        float e2 = __expf(sc[2][r] - m), e3 = __expf(sc[3][r] - m);
        float s = e0 + e1 + e2 + e3;
        s += __shfl_xor(s, 1);
        s += __shfl_xor(s, 2);
        s += __shfl_xor(s, 4);
        s += __shfl_xor(s, 8);
        float inv = 1.0f / s;
        int row = mt4 * 16 + lg * 4 + r;
        sQm[swz128(row, hh * 64 + l16)]      = f2bf(e0 * inv);   // P over Q (own rows/cols)
        sQm[swz128(row, hh * 64 + 16 + l16)] = f2bf(e1 * inv);
        sQm[swz128(row, hh * 64 + 32 + l16)] = f2bf(e2 * inv);
        sQm[swz128(row, hh * 64 + 48 + l16)] = f2bf(e3 * inv);
      }
    }
    // no barrier: P produced and consumed by same wave

    // ---- Phase PV: O = P @ V (write O over P, own region) ----
    {
      f32x4 ov[4] = {};
#pragma unroll
      for (int ks = 0; ks < 2; ++ks) {
        int kbase = ks * 32 + lg * 8;
        short8 a  = lds8(sQm + swz128(mt4 * 16 + l16, hh * 64 + kbase));
        short8 b0 = lds8(sVtm + swzV(hh * 64 + l16, kbase));
        short8 b1 = lds8(sVtm + swzV(hh * 64 + 16 + l16, kbase));
        short8 b2 = lds8(sVtm + swzV(hh * 64 + 32 + l16, kbase));
        short8 b3 = lds8(sVtm + swzV(hh * 64 + 48 + l16, kbase));
        ov[0] = mfma16(a, b0, ov[0]);
        ov[1] = mfma16(a, b1, ov[1]);
        ov[2] = mfma16(a, b2, ov[2]);
        ov[3] = mfma16(a, b3, ov[3]);
      }
#pragma unroll
      for (int r = 0; r < 4; ++r) {
        int row = mt4 * 16 + lg * 4 + r;
        sQm[swz128(row, hh * 64 + l16)]      = f2bf(ov[0][r]);
        sQm[swz128(row, hh * 64 + 16 + l16)] = f2bf(ov[1][r]);
        sQm[swz128(row, hh * 64 + 32 + l16)] = f2bf(ov[2][r]);
        sQm[swz128(row, hh * 64 + 48 + l16)] = f2bf(ov[3][r]);
      }
    }
    __syncthreads();

    // ---- Phase OP: Yacc += O(2 heads) @ Wo[hp*128.., ctg*128..+128] (32x32) ----
    {
      const unsigned short* wo[4];
#pragma unroll
      for (int ct = 0; ct < 4; ++ct)
        wo[ct] = WoT + (size_t)(ctg * 128 + ct * 32 + l32) * 512 + hp * 128;
      short8 wb[2][4];
#pragma unroll
      for (int p = 0; p < 2; ++p)
#pragma unroll
        for (int ct = 0; ct < 4; ++ct)
          wb[p][ct] = *(const short8*)(wo[ct] + p * 16 + kh8);
#pragma unroll
      for (int ks = 0; ks < 8; ++ks) {
        short8 a = lds8(sQm + swz128(rt * 32 + l32, ks * 16 + kh8));
#pragma unroll
        for (int ct = 0; ct < 4; ++ct) {
          short8 w = wb[ks & 1][ct];
          if (ks < 6) wb[ks & 1][ct] = *(const short8*)(wo[ct] + (ks + 2) * 16 + kh8);
          Yacc[ct] = mfma32(a, w, Yacc[ct]);
        }
      }
    }
    __syncthreads();  // next Phase A rewrites sQ/sK/sVt
  }

  // ---- Residual 1 + LayerNorm 1 -> x1 (overwrites sT) ----
  {
#pragma unroll
    for (int ct = 0; ct < 4; ++ct) {
      int col = ctg * 128 + ct * 32 + l32;
      float bv = bo[col];
#pragma unroll
      for (int reg = 0; reg < 16; ++reg) {
        int row = rt * 32 + (reg & 3) + ((reg & 12) << 1) + (kh << 2);
        Yacc[ct][reg] += bv + bf2f(sTm[swzT(row, col)]);
      }
    }
#pragma unroll
    for (int reg = 0; reg < 16; ++reg) {
      float s = Yacc[0][reg] + Yacc[1][reg] + Yacc[2][reg] + Yacc[3][reg];
      float q = Yacc[0][reg] * Yacc[0][reg] + Yacc[1][reg] * Yacc[1][reg] +
                Yacc[2][reg] * Yacc[2][reg] + Yacc[3][reg] * Yacc[3][reg];
      s += __shfl_xor(s, 1);  s += __shfl_xor(s, 2);
      s += __shfl_xor(s, 4);  s += __shfl_xor(s, 8);  s += __shfl_xor(s, 16);
      q += __shfl_xor(q, 1);  q += __shfl_xor(q, 2);
      q += __shfl_xor(q, 4);  q += __shfl_xor(q, 8);  q += __shfl_xor(q, 16);
      if (l32 == 0) {
        int row = rt * 32 + (reg & 3) + ((reg & 12) << 1) + (kh << 2);
        sSum[ctg * 64 + row] = s;
        sSq[ctg * 64 + row]  = q;
      }
    }
    __syncthreads();
    if (tid < 64) {
      float s = sSum[tid] + sSum[64 + tid] + sSum[128 + tid] + sSum[192 + tid];
      float q = sSq[tid] + sSq[64 + tid] + sSq[128 + tid] + sSq[192 + tid];
      float mean = s * (1.0f / 512.0f);
      float var = q * (1.0f / 512.0f) - mean * mean;
      sMean[tid] = mean;
      sRstd[tid] = rsqrtf(var + 1e-5f);
    }
    __syncthreads();
#pragma unroll
    for (int ct = 0; ct < 4; ++ct) {
      int col = ctg * 128 + ct * 32 + l32;
      float gv = g1[col], bv = beta1[col];
#pragma unroll
      for (int reg = 0; reg < 16; ++reg) {
        int row = rt * 32 + (reg & 3) + ((reg & 12) << 1) + (kh << 2);
        float xv = (Yacc[ct][reg] - sMean[row]) * sRstd[row] * gv + bv;
        sTm[swzT(row, col)] = f2bf(xv);
      }
    }
  }
  __syncthreads();

  // ---- FFN: 4 hidden chunks of 128 ----
  f32x16 Facc[4] = {};
  for (int hc = 0; hc < 4; ++hc) {
    // F1: u = relu(x1 @ W1 chunk) (32x32; wave: rows rt*32.., hidden col c128)
    {
      const int hcol = hc * 128 + c128;
      const unsigned short* w1p = W1T + (size_t)hcol * 512;
      f32x16 u = {};
      short8 wbuf[4];
#pragma unroll
      for (int p = 0; p < 4; ++p)
        wbuf[p] = *(const short8*)(w1p + p * 16 + kh8);
#pragma unroll
      for (int ks = 0; ks < 32; ++ks) {
        short8 cw = wbuf[ks & 3];
        if (ks < 28)
          wbuf[ks & 3] = *(const short8*)(w1p + (ks + 4) * 16 + kh8);
        short8 a = lds8(sTm + swzT(arow, ks * 16 + kh8));
        u = mfma32(a, cw, u);
      }
      float bv = bf1[hcol];
#pragma unroll
      for (int reg = 0; reg < 16; ++reg) {
        int row = rt * 32 + (reg & 3) + ((reg & 12) << 1) + (kh << 2);
        sHm[swz128(row, c128)] = f2bf(fmaxf(u[reg] + bv, 0.0f));
      }
    }
    __syncthreads();
    // F2: Facc += u @ W2[hc*128.., ctg*128..+128]
    {
      const unsigned short* w2[4];
#pragma unroll
      for (int ct = 0; ct < 4; ++ct)
        w2[ct] = W2T + (size_t)(ctg * 128 + ct * 32 + l32) * 512 + hc * 128;
      short8 wb[2][4];
#pragma unroll
      for (int p = 0; p < 2; ++p)
#pragma unroll
        for (int ct = 0; ct < 4; ++ct)
          wb[p][ct] = *(const short8*)(w2[ct] + p * 16 + kh8);
#pragma unroll
      for (int ks = 0; ks < 8; ++ks) {
        short8 a = lds8(sHm + swz128(rt * 32 + l32, ks * 16 + kh8));
#pragma unroll
        for (int ct = 0; ct < 4; ++ct) {
          short8 w = wb[ks & 1][ct];
          if (ks < 6) wb[ks & 1][ct] = *(const short8*)(w2[ct] + (ks + 2) * 16 + kh8);
          Facc[ct] = mfma32(a, w, Facc[ct]);
        }
      }
    }
    __syncthreads();  // sH reused next chunk
  }

  // ---- Residual 2 + LayerNorm 2 -> output ----
  {
#pragma unroll
    for (int ct = 0; ct < 4; ++ct) {
      int col = ctg * 128 + ct * 32 + l32;
      float bv = bf2[col];
#pragma unroll
      for (int reg = 0; reg < 16; ++reg) {
        int row = rt * 32 + (reg & 3) + ((reg & 12) << 1) + (kh << 2);
        Facc[ct][reg] += bv + bf2f(sTm[swzT(row, col)]);
      }
    }
#pragma unroll
    for (int reg = 0; reg < 16; ++reg) {
      float s = Facc[0][reg] + Facc[1][reg] + Facc[2][reg] + Facc[3][reg];
      float q = Facc[0][reg] * Facc[0][reg] + Facc[1][reg] * Facc[1][reg] +
                Facc[2][reg] * Facc[2][reg] + Facc[3][reg] * Facc[3][reg];
      s += __shfl_xor(s, 1);  s += __shfl_xor(s, 2);
      s += __shfl_xor(s, 4);  s += __shfl_xor(s, 8);  s += __shfl_xor(s, 16);
      q += __shfl_xor(q, 1);  q += __shfl_xor(q, 2);
      q += __shfl_xor(q, 4);  q += __shfl_xor(q, 8);  q += __shfl_xor(q, 16);
      if (l32 == 0) {
        int row = rt * 32 + (reg & 3) + ((reg & 12) << 1) + (kh << 2);
        sSum[ctg * 64 + row] = s;
        sSq[ctg * 64 + row]  = q;
      }
    }
    __syncthreads();
    if (tid < 64) {
      float s = sSum[tid] + sSum[64 + tid] + sSum[128 + tid] + sSum[192 + tid];
      float q = sSq[tid] + sSq[64 + tid] + sSq[128 + tid] + sSq[192 + tid];
      float mean = s * (1.0f / 512.0f);
      float var = q * (1.0f / 512.0f) - mean * mean;
      sMean[tid] = mean;
      sRstd[tid] = rsqrtf(var + 1e-5f);
    }
    __syncthreads();
#pragma unroll
    for (int ct = 0; ct < 4; ++ct) {
      int col = ctg * 128 + ct * 32 + l32;
      float gv = g2[col], bv = beta2[col];
      float* op = ob + (size_t)col * 9216;
#pragma unroll
      for (int q4 = 0; q4 < 4; ++q4) {
        int t0 = rt * 32 + q4 * 8 + (kh << 2);
        float4 o4;
        o4.x = (Facc[ct][4 * q4 + 0] - sMean[t0 + 0]) * sRstd[t0 + 0] * gv + bv;
        o4.y = (Facc[ct][4 * q4 + 1] - sMean[t0 + 1]) * sRstd[t0 + 1] * gv + bv;
        o4.z = (Facc[ct][4 * q4 + 2] - sMean[t0 + 2]) * sRstd[t0 + 2] * gv + bv;
        o4.w = (Facc[ct][4 * q4 + 3] - sMean[t0 + 3]) * sRstd[t0 + 3] * gv + bv;
        *reinterpret_cast<float4*>(op + (t0 >> 3) * 96 + (t0 & 7)) = o4;
      }
    }
  }
}

extern "C" void kernel_launch(void* const* d_in, const int* in_sizes, int n_in,
                              void* d_out, int out_size, void* d_ws, size_t ws_size,
                              hipStream_t stream) {
  const float* x     = (const float*)d_in[0];
  const float* Wqkv  = (const float*)d_in[1];
  const float* bqkv  = (const float*)d_in[2];
  const float* Wo    = (const float*)d_in[3];
  const float* bo    = (const float*)d_in[4];
  const float* g1    = (const float*)d_in[5];
  const float* beta1 = (const float*)d_in[6];
  const float* W1    = (const float*)d_in[7];
  const float* bf1   = (const float*)d_in[8];
  const float* W2    = (const float*)d_in[9];
  const float* bf2   = (const float*)d_in[10];
  const float* g2    = (const float*)d_in[11];
  const float* beta2 = (const float*)d_in[12];
  float* out = (float*)d_out;

  unsigned short* ws = (unsigned short*)d_ws;
  unsigned short* WqkvT = ws;                          // 1536*512
  unsigned short* WoT   = ws + (size_t)1536 * 512;
  unsigned short* W1T   = WoT + (size_t)512 * 512;
  unsigned short* W2T   = W1T + (size_t)512 * 512;

  transpose_cvt_kernel<<<dim3(48, 16), 256, 0, stream>>>(Wqkv, WqkvT, 512, 1536);
  transpose_cvt_kernel<<<dim3(16, 16), 256, 0, stream>>>(Wo, WoT, 512, 512);
  transpose_cvt_kernel<<<dim3(16, 16), 256, 0, stream>>>(W1, W1T, 512, 512);
  transpose_cvt_kernel<<<dim3(16, 16), 256, 0, stream>>>(W2, W2T, 512, 512);

  (void)hipFuncSetAttribute((const void*)swin_fused,
                            hipFuncAttributeMaxDynamicSharedMemorySize, SMEM_BYTES);
  swin_fused<<<NWIN, 512, SMEM_BYTES, stream>>>(x, WqkvT, bqkv, WoT, bo, g1, beta1,
                                                W1T, bf1, W2T, bf2, g2, beta2, out);
}

// Round 7
// 2025.134 us; speedup vs baseline: 1.0182x; 1.0134x over previous
//
#include <hip/hip_runtime.h>

typedef short short8 __attribute__((ext_vector_type(8)));
typedef float f32x4 __attribute__((ext_vector_type(4)));
typedef float f32x16 __attribute__((ext_vector_type(16)));

#define NWIN 2304
#define SMEM_BYTES 163840

static __device__ __forceinline__ unsigned short f2bf(float f) {
  unsigned int u = __float_as_uint(f);
  u += 0x7FFFu + ((u >> 16) & 1u);   // RNE
  return (unsigned short)(u >> 16);
}
static __device__ __forceinline__ float bf2f(unsigned short s) {
  return __uint_as_float(((unsigned int)s) << 16);
}
static __device__ __forceinline__ f32x4 mfma16(short8 a, short8 b, f32x4 c) {
  return __builtin_amdgcn_mfma_f32_16x16x32_bf16(a, b, c, 0, 0, 0);
}
static __device__ __forceinline__ f32x16 mfma32(short8 a, short8 b, f32x16 c) {
  return __builtin_amdgcn_mfma_f32_32x32x16_bf16(a, b, c, 0, 0, 0);
}
static __device__ __forceinline__ short8 lds8(const unsigned short* p) {
  return *reinterpret_cast<const short8*>(p);
}
// XOR swizzles: 16B granule, spread by low row bits (bank-balanced b128 reads)
static __device__ __forceinline__ int swzT(int r, int c) {   // [64][512]
  return r * 512 + ((((c >> 3) ^ (r & 7)) << 3) | (c & 7));
}
static __device__ __forceinline__ int swz128(int r, int c) { // [64][128]
  return r * 128 + ((((c >> 3) ^ (r & 7)) << 3) | (c & 7));
}
static __device__ __forceinline__ int swzV(int r, int c) {   // [128][64]
  return r * 64 + ((((c >> 3) ^ (r & 7)) << 3) | (c & 7));
}

// ---- weight prep: in[K][N] f32  ->  out[N][K] bf16 ----
__global__ void transpose_cvt_kernel(const float* __restrict__ in,
                                     unsigned short* __restrict__ out,
                                     int K, int N) {
  __shared__ float tile[32][33];
  int bn = blockIdx.x * 32, bk = blockIdx.y * 32;
  int tx = threadIdx.x & 31, ty = threadIdx.x >> 5;  // 256 thr: 32 x 8
#pragma unroll
  for (int r = 0; r < 32; r += 8)
    tile[ty + r][tx] = in[(size_t)(bk + ty + r) * N + bn + tx];
  __syncthreads();
#pragma unroll
  for (int r = 0; r < 32; r += 8)
    out[(size_t)(bn + ty + r) * K + bk + tx] = f2bf(tile[tx][ty + r]);
}

__global__ __launch_bounds__(512, 2)
void swin_fused(const float* __restrict__ x,
                const unsigned short* __restrict__ WqkvT,  // [1536][512] bf16
                const float* __restrict__ bqkv,
                const unsigned short* __restrict__ WoT,    // [512][512]
                const float* __restrict__ bo,
                const float* __restrict__ g1, const float* __restrict__ beta1,
                const unsigned short* __restrict__ W1T,    // [512][512]
                const float* __restrict__ bf1,
                const unsigned short* __restrict__ W2T,    // [512][512]
                const float* __restrict__ bf2,
                const float* __restrict__ g2, const float* __restrict__ beta2,
                float* __restrict__ out) {
  extern __shared__ unsigned char smem[];
  unsigned short* sTm   = (unsigned short*)smem;             // [64][512] swz: t / x1
  unsigned short* sOall = (unsigned short*)(smem + 65536);   // [64][512] swz: Q->P->O (all heads)
  unsigned short* sKm   = (unsigned short*)(smem + 131072);  // [64][128] swz: K / hidden U
  unsigned short* sVtm  = (unsigned short*)(smem + 147456);  // [128][64] swz: V^T (attn only)
  // reductions overlay sVtm (dead outside attention)
  float* sSum  = (float*)(smem + 147456);                    // [4][64]
  float* sSq   = (float*)(smem + 148480);                    // [4][64]
  float* sMean = (float*)(smem + 149504);                    // [64]
  float* sRstd = (float*)(smem + 149760);                    // [64]

  const int tid = threadIdx.x;
  const int wvid = tid >> 6, lane = tid & 63;
  const int l16 = lane & 15, lg = lane >> 4;
  const int l32 = lane & 31, kh = lane >> 5, kh8 = kh << 3;

  // XCD swizzle
  const int wid = (blockIdx.x & 7) * 288 + (blockIdx.x >> 3);
  const int b = wid / 144, rem = wid % 144;
  const int h0 = (rem / 12) * 8, w0 = (rem % 12) * 8;
  const float* xb = x + (size_t)b * 512 * 9216 + (size_t)h0 * 96 + w0;
  float* ob = out + (size_t)b * 512 * 9216 + (size_t)h0 * 96 + w0;

  // wave roles
  const int rt = wvid & 1;          // 32-row tile (A / OP / F1 / F2 / LN)
  const int g4 = wvid >> 1;         // 32-col group within 128 (A / F1)
  const int ctg = wvid >> 1;        // 128-col group within 512 (OP / F2 / LN)
  const int hh = wvid >> 2;         // head within pair (S / PV)
  const int mt4 = wvid & 3;         // 16-row tile (S / PV)
  const int c128 = g4 * 32 + l32;   // col within 128 (A / F1)
  const int arow = rt * 32 + l32;   // A-frag row (32x32 MFMA)

  // ---- Phase 0: gather window -> sT (bf16, swizzled) ----
#pragma unroll
  for (int it = 0; it < 16; ++it) {
    int gid = it * 512 + tid;                 // gid = c*16 + hr*2 + wq
    int c = gid >> 4, hr = (gid >> 1) & 7, wq = gid & 1;
    float4 v = *reinterpret_cast<const float4*>(xb + (size_t)c * 9216 + hr * 96 + wq * 4);
    int tok = hr * 8 + wq * 4;
    sTm[swzT(tok + 0, c)] = f2bf(v.x);
    sTm[swzT(tok + 1, c)] = f2bf(v.y);
    sTm[swzT(tok + 2, c)] = f2bf(v.z);
    sTm[swzT(tok + 3, c)] = f2bf(v.w);
  }
  __syncthreads();

  for (int hp = 0; hp < 4; ++hp) {   // head pairs
    // ---- Phase A: q,k,v (wave: rows rt*32..+32, qkv cols c128; 32x32 MFMA) ----
    {
      const unsigned short* bq = WqkvT + (size_t)(hp * 128 + c128) * 512;
      const unsigned short* bk = bq + (size_t)512 * 512;
      const unsigned short* bv = bq + (size_t)1024 * 512;
      f32x16 aq = {}, ak = {}, av = {};
      short8 qw[4], kw[4], vw[4];
#pragma unroll
      for (int p = 0; p < 4; ++p) {
        int ko = p * 16 + kh8;
        qw[p] = *(const short8*)(bq + ko);
        kw[p] = *(const short8*)(bk + ko);
        vw[p] = *(const short8*)(bv + ko);
      }
#pragma unroll
      for (int ks = 0; ks < 32; ++ks) {
        short8 cq = qw[ks & 3], ck = kw[ks & 3], cv = vw[ks & 3];
        if (ks < 28) {
          int ko = (ks + 4) * 16 + kh8;
          qw[ks & 3] = *(const short8*)(bq + ko);
          kw[ks & 3] = *(const short8*)(bk + ko);
          vw[ks & 3] = *(const short8*)(bv + ko);
        }
        short8 a = lds8(sTm + swzT(arow, ks * 16 + kh8));
        aq = mfma32(a, cq, aq);
        ak = mfma32(a, ck, ak);
        av = mfma32(a, cv, av);
      }
      const float bqv = bqkv[hp * 128 + c128];
      const float bkv = bqkv[512 + hp * 128 + c128];
      const float bvv = bqkv[1024 + hp * 128 + c128];
#pragma unroll
      for (int reg = 0; reg < 16; ++reg) {
        int row = rt * 32 + (reg & 3) + ((reg & 12) << 1) + (kh << 2);
        sOall[swzT(row, hp * 128 + c128)] = f2bf((aq[reg] + bqv) * 0.125f);
        sKm[swz128(row, c128)] = f2bf(ak[reg] + bkv);
      }
#pragma unroll
      for (int q = 0; q < 4; ++q) {
        int t0 = rt * 32 + q * 8 + (kh << 2);
        ushort4 pk;
        pk.x = f2bf(av[4 * q + 0] + bvv);
        pk.y = f2bf(av[4 * q + 1] + bvv);
        pk.z = f2bf(av[4 * q + 2] + bvv);
        pk.w = f2bf(av[4 * q + 3] + bvv);
        *reinterpret_cast<ushort4*>(sVtm + swzV(c128, t0)) = pk;
      }
    }
    __syncthreads();

    // ---- Phase S: scores + wave-local softmax (16x16; head hh, rows mt4*16..) ----
    {
      f32x4 sc[4] = {};
#pragma unroll
      for (int ks = 0; ks < 2; ++ks) {
        int kq = hp * 128 + hh * 64 + ks * 32 + lg * 8;
        int kk = hh * 64 + ks * 32 + lg * 8;
        short8 a  = lds8(sOall + swzT(mt4 * 16 + l16, kq));
        short8 b0 = lds8(sKm + swz128(l16, kk));
        short8 b1 = lds8(sKm + swz128(16 + l16, kk));
        short8 b2 = lds8(sKm + swz128(32 + l16, kk));
        short8 b3 = lds8(sKm + swz128(48 + l16, kk));
        sc[0] = mfma16(a, b0, sc[0]);
        sc[1] = mfma16(a, b1, sc[1]);
        sc[2] = mfma16(a, b2, sc[2]);
        sc[3] = mfma16(a, b3, sc[3]);
      }
#pragma unroll
      for (int r = 0; r < 4; ++r) {
        float m = fmaxf(fmaxf(sc[0][r], sc[1][r]), fmaxf(sc[2][r], sc[3][r]));
        m = fmaxf(m, __shfl_xor(m, 1));
        m = fmaxf(m, __shfl_xor(m, 2));
        m = fmaxf(m, __shfl_xor(m, 4));
        m = fmaxf(m, __shfl_xor(m, 8));
        float e0 = __expf(sc[0][r] - m), e1 = __expf(sc[1][r] - m);
        float e2 = __expf(sc[2][r] - m), e3 = __expf(sc[3][r] - m);
        float s = e0 + e1 + e2 + e3;
        s += __shfl_xor(s, 1);
        s += __shfl_xor(s, 2);
        s += __shfl_xor(s, 4);
        s += __shfl_xor(s, 8);
        float inv = 1.0f / s;
        int row = mt4 * 16 + lg * 4 + r;
        int cb = hp * 128 + hh * 64;
        sOall[swzT(row, cb + l16)]      = f2bf(e0 * inv);   // P over Q (own rows/cols)
        sOall[swzT(row, cb + 16 + l16)] = f2bf(e1 * inv);
        sOall[swzT(row, cb + 32 + l16)] = f2bf(e2 * inv);
        sOall[swzT(row, cb + 48 + l16)] = f2bf(e3 * inv);
      }
    }
    // no barrier: P produced and consumed by same wave

    // ---- Phase PV: O = P @ V (write O over P, own region) ----
    {
      f32x4 ov[4] = {};
#pragma unroll
      for (int ks = 0; ks < 2; ++ks) {
        int kbase = ks * 32 + lg * 8;
        short8 a  = lds8(sOall + swzT(mt4 * 16 + l16, hp * 128 + hh * 64 + kbase));
        short8 b0 = lds8(sVtm + swzV(hh * 64 + l16, kbase));
        short8 b1 = lds8(sVtm + swzV(hh * 64 + 16 + l16, kbase));
        short8 b2 = lds8(sVtm + swzV(hh * 64 + 32 + l16, kbase));
        short8 b3 = lds8(sVtm + swzV(hh * 64 + 48 + l16, kbase));
        ov[0] = mfma16(a, b0, ov[0]);
        ov[1] = mfma16(a, b1, ov[1]);
        ov[2] = mfma16(a, b2, ov[2]);
        ov[3] = mfma16(a, b3, ov[3]);
      }
#pragma unroll
      for (int r = 0; r < 4; ++r) {
        int row = mt4 * 16 + lg * 4 + r;
        int cb = hp * 128 + hh * 64;
        sOall[swzT(row, cb + l16)]      = f2bf(ov[0][r]);
        sOall[swzT(row, cb + 16 + l16)] = f2bf(ov[1][r]);
        sOall[swzT(row, cb + 32 + l16)] = f2bf(ov[2][r]);
        sOall[swzT(row, cb + 48 + l16)] = f2bf(ov[3][r]);
      }
    }
    __syncthreads();  // next Phase A rewrites sKm/sVtm; O slice stays
  }

  // ---- Phase OP: Y = O @ Wo (single K=512 streaming GEMM; Yacc live only here) ----
  f32x16 Yacc[4] = {};
  {
    const unsigned short* wo[4];
#pragma unroll
    for (int ct = 0; ct < 4; ++ct)
      wo[ct] = WoT + (size_t)(ctg * 128 + ct * 32 + l32) * 512;
    short8 wb[2][4];
#pragma unroll
    for (int p = 0; p < 2; ++p)
#pragma unroll
      for (int ct = 0; ct < 4; ++ct)
        wb[p][ct] = *(const short8*)(wo[ct] + p * 16 + kh8);
#pragma unroll
    for (int ks = 0; ks < 32; ++ks) {
      short8 a = lds8(sOall + swzT(arow, ks * 16 + kh8));
#pragma unroll
      for (int ct = 0; ct < 4; ++ct) {
        short8 w = wb[ks & 1][ct];
        if (ks < 30) wb[ks & 1][ct] = *(const short8*)(wo[ct] + (ks + 2) * 16 + kh8);
        Yacc[ct] = mfma32(a, w, Yacc[ct]);
      }
    }
  }

  // ---- Residual 1 + LayerNorm 1 -> x1 (overwrites sT) ----
  {
#pragma unroll
    for (int ct = 0; ct < 4; ++ct) {
      int col = ctg * 128 + ct * 32 + l32;
      float bv = bo[col];
#pragma unroll
      for (int reg = 0; reg < 16; ++reg) {
        int row = rt * 32 + (reg & 3) + ((reg & 12) << 1) + (kh << 2);
        Yacc[ct][reg] += bv + bf2f(sTm[swzT(row, col)]);
      }
    }
#pragma unroll
    for (int reg = 0; reg < 16; ++reg) {
      float s = Yacc[0][reg] + Yacc[1][reg] + Yacc[2][reg] + Yacc[3][reg];
      float q = Yacc[0][reg] * Yacc[0][reg] + Yacc[1][reg] * Yacc[1][reg] +
                Yacc[2][reg] * Yacc[2][reg] + Yacc[3][reg] * Yacc[3][reg];
      s += __shfl_xor(s, 1);  s += __shfl_xor(s, 2);
      s += __shfl_xor(s, 4);  s += __shfl_xor(s, 8);  s += __shfl_xor(s, 16);
      q += __shfl_xor(q, 1);  q += __shfl_xor(q, 2);
      q += __shfl_xor(q, 4);  q += __shfl_xor(q, 8);  q += __shfl_xor(q, 16);
      if (l32 == 0) {
        int row = rt * 32 + (reg & 3) + ((reg & 12) << 1) + (kh << 2);
        sSum[ctg * 64 + row] = s;
        sSq[ctg * 64 + row]  = q;
      }
    }
    __syncthreads();
    if (tid < 64) {
      float s = sSum[tid] + sSum[64 + tid] + sSum[128 + tid] + sSum[192 + tid];
      float q = sSq[tid] + sSq[64 + tid] + sSq[128 + tid] + sSq[192 + tid];
      float mean = s * (1.0f / 512.0f);
      float var = q * (1.0f / 512.0f) - mean * mean;
      sMean[tid] = mean;
      sRstd[tid] = rsqrtf(var + 1e-5f);
    }
    __syncthreads();
#pragma unroll
    for (int ct = 0; ct < 4; ++ct) {
      int col = ctg * 128 + ct * 32 + l32;
      float gv = g1[col], bv = beta1[col];
#pragma unroll
      for (int reg = 0; reg < 16; ++reg) {
        int row = rt * 32 + (reg & 3) + ((reg & 12) << 1) + (kh << 2);
        float xv = (Yacc[ct][reg] - sMean[row]) * sRstd[row] * gv + bv;
        sTm[swzT(row, col)] = f2bf(xv);
      }
    }
  }
  __syncthreads();

  // ---- FFN: 4 hidden chunks of 128 ----
  f32x16 Facc[4] = {};
  for (int hc = 0; hc < 4; ++hc) {
    // F1: u = relu(x1 @ W1 chunk) (32x32; wave: rows rt*32.., hidden col c128)
    {
      const int hcol = hc * 128 + c128;
      const unsigned short* w1p = W1T + (size_t)hcol * 512;
      f32x16 u = {};
      short8 wbuf[4];
#pragma unroll
      for (int p = 0; p < 4; ++p)
        wbuf[p] = *(const short8*)(w1p + p * 16 + kh8);
#pragma unroll
      for (int ks = 0; ks < 32; ++ks) {
        short8 cw = wbuf[ks & 3];
        if (ks < 28)
          wbuf[ks & 3] = *(const short8*)(w1p + (ks + 4) * 16 + kh8);
        short8 a = lds8(sTm + swzT(arow, ks * 16 + kh8));
        u = mfma32(a, cw, u);
      }
      float bv = bf1[hcol];
#pragma unroll
      for (int reg = 0; reg < 16; ++reg) {
        int row = rt * 32 + (reg & 3) + ((reg & 12) << 1) + (kh << 2);
        sKm[swz128(row, c128)] = f2bf(fmaxf(u[reg] + bv, 0.0f));
      }
    }
    __syncthreads();
    // F2: Facc += u @ W2[hc*128.., ctg*128..+128]
    {
      const unsigned short* w2[4];
#pragma unroll
      for (int ct = 0; ct < 4; ++ct)
        w2[ct] = W2T + (size_t)(ctg * 128 + ct * 32 + l32) * 512 + hc * 128;
      short8 wb[2][4];
#pragma unroll
      for (int p = 0; p < 2; ++p)
#pragma unroll
        for (int ct = 0; ct < 4; ++ct)
          wb[p][ct] = *(const short8*)(w2[ct] + p * 16 + kh8);
#pragma unroll
      for (int ks = 0; ks < 8; ++ks) {
        short8 a = lds8(sKm + swz128(rt * 32 + l32, ks * 16 + kh8));
#pragma unroll
        for (int ct = 0; ct < 4; ++ct) {
          short8 w = wb[ks & 1][ct];
          if (ks < 6) wb[ks & 1][ct] = *(const short8*)(w2[ct] + (ks + 2) * 16 + kh8);
          Facc[ct] = mfma32(a, w, Facc[ct]);
        }
      }
    }
    __syncthreads();  // sKm reused next chunk
  }

  // ---- Residual 2 + LayerNorm 2 -> output ----
  {
#pragma unroll
    for (int ct = 0; ct < 4; ++ct) {
      int col = ctg * 128 + ct * 32 + l32;
      float bv = bf2[col];
#pragma unroll
      for (int reg = 0; reg < 16; ++reg) {
        int row = rt * 32 + (reg & 3) + ((reg & 12) << 1) + (kh << 2);
        Facc[ct][reg] += bv + bf2f(sTm[swzT(row, col)]);
      }
    }
#pragma unroll
    for (int reg = 0; reg < 16; ++reg) {
      float s = Facc[0][reg] + Facc[1][reg] + Facc[2][reg] + Facc[3][reg];
      float q = Facc[0][reg] * Facc[0][reg] + Facc[1][reg] * Facc[1][reg] +
                Facc[2][reg] * Facc[2][reg] + Facc[3][reg] * Facc[3][reg];
      s += __shfl_xor(s, 1);  s += __shfl_xor(s, 2);
      s += __shfl_xor(s, 4);  s += __shfl_xor(s, 8);  s += __shfl_xor(s, 16);
      q += __shfl_xor(q, 1);  q += __shfl_xor(q, 2);
      q += __shfl_xor(q, 4);  q += __shfl_xor(q, 8);  q += __shfl_xor(q, 16);
      if (l32 == 0) {
        int row = rt * 32 + (reg & 3) + ((reg & 12) << 1) + (kh << 2);
        sSum[ctg * 64 + row] = s;
        sSq[ctg * 64 + row]  = q;
      }
    }
    __syncthreads();
    if (tid < 64) {
      float s = sSum[tid] + sSum[64 + tid] + sSum[128 + tid] + sSum[192 + tid];
      float q = sSq[tid] + sSq[64 + tid] + sSq[128 + tid] + sSq[192 + tid];
      float mean = s * (1.0f / 512.0f);
      float var = q * (1.0f / 512.0f) - mean * mean;
      sMean[tid] = mean;
      sRstd[tid] = rsqrtf(var + 1e-5f);
    }
    __syncthreads();
#pragma unroll
    for (int ct = 0; ct < 4; ++ct) {
      int col = ctg * 128 + ct * 32 + l32;
      float gv = g2[col], bv = beta2[col];
      float* op = ob + (size_t)col * 9216;
#pragma unroll
      for (int q4 = 0; q4 < 4; ++q4) {
        int t0 = rt * 32 + q4 * 8 + (kh << 2);
        float4 o4;
        o4.x = (Facc[ct][4 * q4 + 0] - sMean[t0 + 0]) * sRstd[t0 + 0] * gv + bv;
        o4.y = (Facc[ct][4 * q4 + 1] - sMean[t0 + 1]) * sRstd[t0 + 1] * gv + bv;
        o4.z = (Facc[ct][4 * q4 + 2] - sMean[t0 + 2]) * sRstd[t0 + 2] * gv + bv;
        o4.w = (Facc[ct][4 * q4 + 3] - sMean[t0 + 3]) * sRstd[t0 + 3] * gv + bv;
        *reinterpret_cast<float4*>(op + (t0 >> 3) * 96 + (t0 & 7)) = o4;
      }
    }
  }
}

extern "C" void kernel_launch(void* const* d_in, const int* in_sizes, int n_in,
                              void* d_out, int out_size, void* d_ws, size_t ws_size,
                              hipStream_t stream) {
  const float* x     = (const float*)d_in[0];
  const float* Wqkv  = (const float*)d_in[1];
  const float* bqkv  = (const float*)d_in[2];
  const float* Wo    = (const float*)d_in[3];
  const float* bo    = (const float*)d_in[4];
  const float* g1    = (const float*)d_in[5];
  const float* beta1 = (const float*)d_in[6];
  const float* W1    = (const float*)d_in[7];
  const float* bf1   = (const float*)d_in[8];
  const float* W2    = (const float*)d_in[9];
  const float* bf2   = (const float*)d_in[10];
  const float* g2    = (const float*)d_in[11];
  const float* beta2 = (const float*)d_in[12];
  float* out = (float*)d_out;

  unsigned short* ws = (unsigned short*)d_ws;
  unsigned short* WqkvT = ws;                          // 1536*512
  unsigned short* WoT   = ws + (size_t)1536 * 512;
  unsigned short* W1T   = WoT + (size_t)512 * 512;
  unsigned short* W2T   = W1T + (size_t)512 * 512;

  transpose_cvt_kernel<<<dim3(48, 16), 256, 0, stream>>>(Wqkv, WqkvT, 512, 1536);
  transpose_cvt_kernel<<<dim3(16, 16), 256, 0, stream>>>(Wo, WoT, 512, 512);
  transpose_cvt_kernel<<<dim3(16, 16), 256, 0, stream>>>(W1, W1T, 512, 512);
  transpose_cvt_kernel<<<dim3(16, 16), 256, 0, stream>>>(W2, W2T, 512, 512);

  (void)hipFuncSetAttribute((const void*)swin_fused,
                            hipFuncAttributeMaxDynamicSharedMemorySize, SMEM_BYTES);
  swin_fused<<<NWIN, 512, SMEM_BYTES, stream>>>(x, WqkvT, bqkv, WoT, bo, g1, beta1,
                                                W1T, bf1, W2T, bf2, g2, beta2, out);
}

// Round 8
// 1927.357 us; speedup vs baseline: 1.0699x; 1.0507x over previous
//
#include <hip/hip_runtime.h>

typedef short short8 __attribute__((ext_vector_type(8)));
typedef float f32x4 __attribute__((ext_vector_type(4)));

#define NWIN 2304
#define SMEM_BYTES 163840

static __device__ __forceinline__ unsigned short f2bf(float f) {
  unsigned int u = __float_as_uint(f);
  u += 0x7FFFu + ((u >> 16) & 1u);   // RNE
  return (unsigned short)(u >> 16);
}
static __device__ __forceinline__ float bf2f(unsigned short s) {
  return __uint_as_float(((unsigned int)s) << 16);
}
static __device__ __forceinline__ f32x4 mfma16(short8 a, short8 b, f32x4 c) {
  return __builtin_amdgcn_mfma_f32_16x16x32_bf16(a, b, c, 0, 0, 0);
}
static __device__ __forceinline__ short8 lds8(const unsigned short* p) {
  return *reinterpret_cast<const short8*>(p);
}
// XOR swizzles: 16B granule, spread by low row bits (bank-balanced b128 reads)
static __device__ __forceinline__ int swzT(int r, int c) {   // [64][512]
  return r * 512 + ((((c >> 3) ^ (r & 7)) << 3) | (c & 7));
}
static __device__ __forceinline__ int swz128(int r, int c) { // [64][128]
  return r * 128 + ((((c >> 3) ^ (r & 7)) << 3) | (c & 7));
}
static __device__ __forceinline__ int swzV(int r, int c) {   // [128][64]
  return r * 64 + ((((c >> 3) ^ (r & 7)) << 3) | (c & 7));
}

// ---- weight prep: in[K][N] f32  ->  out[N][K] bf16 ----
__global__ void transpose_cvt_kernel(const float* __restrict__ in,
                                     unsigned short* __restrict__ out,
                                     int K, int N) {
  __shared__ float tile[32][33];
  int bn = blockIdx.x * 32, bk = blockIdx.y * 32;
  int tx = threadIdx.x & 31, ty = threadIdx.x >> 5;  // 256 thr: 32 x 8
#pragma unroll
  for (int r = 0; r < 32; r += 8)
    tile[ty + r][tx] = in[(size_t)(bk + ty + r) * N + bn + tx];
  __syncthreads();
#pragma unroll
  for (int r = 0; r < 32; r += 8)
    out[(size_t)(bn + ty + r) * K + bk + tx] = f2bf(tile[tx][ty + r]);
}

__global__ __launch_bounds__(1024)
__attribute__((amdgpu_waves_per_eu(4, 4)))
void swin_fused(const float* __restrict__ x,
                const unsigned short* __restrict__ WqkvT,  // [1536][512] bf16
                const float* __restrict__ bqkv,
                const unsigned short* __restrict__ WoT,    // [512][512]
                const float* __restrict__ bo,
                const float* __restrict__ g1, const float* __restrict__ beta1,
                const unsigned short* __restrict__ W1T,    // [512][512]
                const float* __restrict__ bf1,
                const unsigned short* __restrict__ W2T,    // [512][512]
                const float* __restrict__ bf2,
                const float* __restrict__ g2, const float* __restrict__ beta2,
                float* __restrict__ out) {
  extern __shared__ unsigned char smem[];
  unsigned short* sTm   = (unsigned short*)smem;             // [64][512] swz: t / x1
  unsigned short* sOall = (unsigned short*)(smem + 65536);   // [64][512] swz: Q->P->O
  unsigned short* sKm   = (unsigned short*)(smem + 131072);  // [64][128] swz: K / hidden U
  unsigned short* sVtm  = (unsigned short*)(smem + 147456);  // [128][64] swz: V^T (attn only)
  // reductions overlay sVtm (dead outside attention)
  float* sSum  = (float*)(smem + 147456);                    // [16][64]
  float* sSq   = (float*)(smem + 151552);                    // [16][64]
  float* sMean = (float*)(smem + 155648);                    // [64]
  float* sRstd = (float*)(smem + 155904);                    // [64]

  const int tid = threadIdx.x;
  const int wvid = tid >> 6, lane = tid & 63;
  const int l16 = lane & 15, lg = lane >> 4;

  // XCD swizzle
  const int wid = (blockIdx.x & 7) * 288 + (blockIdx.x >> 3);
  const int b = wid / 144, rem = wid % 144;
  const int h0 = (rem / 12) * 8, w0 = (rem % 12) * 8;
  const float* xb = x + (size_t)b * 512 * 9216 + (size_t)h0 * 96 + w0;
  float* ob = out + (size_t)b * 512 * 9216 + (size_t)h0 * 96 + w0;

  // wave roles
  const int rt2 = wvid & 1;         // 32-row half (A / F1)
  const int cs8 = wvid >> 1;        // 16-col slice within 128 (A / F1)
  const int c2 = cs8 * 16 + l16;    // col within 128 (A / F1)
  const int hh = wvid >> 2;         // head within pair (S / PV; wvid<8)
  const int mt4 = wvid & 3;         // 16-row tile (S / PV)
  const int nc0 = wvid * 32;        // wave's 32 cols of 512 (OP / F2 / LN)

  // ---- Phase 0: gather window -> sT (bf16, swizzled) ----
#pragma unroll
  for (int it = 0; it < 8; ++it) {
    int gid = it * 1024 + tid;                // gid = c*16 + hr*2 + wq
    int c = gid >> 4, hr = (gid >> 1) & 7, wq = gid & 1;
    float4 v = *reinterpret_cast<const float4*>(xb + (size_t)c * 9216 + hr * 96 + wq * 4);
    int tok = hr * 8 + wq * 4;
    sTm[swzT(tok + 0, c)] = f2bf(v.x);
    sTm[swzT(tok + 1, c)] = f2bf(v.y);
    sTm[swzT(tok + 2, c)] = f2bf(v.z);
    sTm[swzT(tok + 3, c)] = f2bf(v.w);
  }
  __syncthreads();

  for (int hp = 0; hp < 4; ++hp) {   // head pairs
    // ---- Phase A: q,k,v (wave: 32 rows x 16 qkv-cols x 3 mats, depth-2 prefetch) ----
    {
      const unsigned short* bq = WqkvT + (size_t)(hp * 128 + c2) * 512;
      const unsigned short* bk = bq + (size_t)512 * 512;
      const unsigned short* bv = bq + (size_t)1024 * 512;
      f32x4 acc[3][2] = {};
      short8 qw[2], kw[2], vw[2];
#pragma unroll
      for (int p = 0; p < 2; ++p) {
        int ko = p * 32 + lg * 8;
        qw[p] = *(const short8*)(bq + ko);
        kw[p] = *(const short8*)(bk + ko);
        vw[p] = *(const short8*)(bv + ko);
      }
#pragma unroll
      for (int ks = 0; ks < 16; ++ks) {
        const int ko = ks * 32 + lg * 8;
        short8 cq = qw[ks & 1], ck = kw[ks & 1], cv = vw[ks & 1];
        if (ks < 14) {
          int ko2 = (ks + 2) * 32 + lg * 8;
          qw[ks & 1] = *(const short8*)(bq + ko2);
          kw[ks & 1] = *(const short8*)(bk + ko2);
          vw[ks & 1] = *(const short8*)(bv + ko2);
        }
        short8 a0 = lds8(sTm + swzT(rt2 * 32 + l16, ko));
        short8 a1 = lds8(sTm + swzT(rt2 * 32 + 16 + l16, ko));
        acc[0][0] = mfma16(a0, cq, acc[0][0]);
        acc[0][1] = mfma16(a1, cq, acc[0][1]);
        acc[1][0] = mfma16(a0, ck, acc[1][0]);
        acc[1][1] = mfma16(a1, ck, acc[1][1]);
        acc[2][0] = mfma16(a0, cv, acc[2][0]);
        acc[2][1] = mfma16(a1, cv, acc[2][1]);
      }
      const float bqv = bqkv[hp * 128 + c2];
      const float bkv = bqkv[512 + hp * 128 + c2];
      const float bvv = bqkv[1024 + hp * 128 + c2];
#pragma unroll
      for (int mt2 = 0; mt2 < 2; ++mt2) {
        int tok0 = rt2 * 32 + mt2 * 16 + lg * 4;
#pragma unroll
        for (int r = 0; r < 4; ++r) {
          sOall[swzT(tok0 + r, hp * 128 + c2)] = f2bf((acc[0][mt2][r] + bqv) * 0.125f);
          sKm[swz128(tok0 + r, c2)] = f2bf(acc[1][mt2][r] + bkv);
        }
        ushort4 pk;
        pk.x = f2bf(acc[2][mt2][0] + bvv);
        pk.y = f2bf(acc[2][mt2][1] + bvv);
        pk.z = f2bf(acc[2][mt2][2] + bvv);
        pk.w = f2bf(acc[2][mt2][3] + bvv);
        *reinterpret_cast<ushort4*>(sVtm + swzV(c2, tok0)) = pk;
      }
    }
    __syncthreads();

    // ---- Phase S + PV (8 active waves: head hh, rows mt4*16..) ----
    if (wvid < 8) {
      f32x4 sc[4] = {};
#pragma unroll
      for (int ks = 0; ks < 2; ++ks) {
        int kq = hp * 128 + hh * 64 + ks * 32 + lg * 8;
        int kk = hh * 64 + ks * 32 + lg * 8;
        short8 a  = lds8(sOall + swzT(mt4 * 16 + l16, kq));
        short8 b0 = lds8(sKm + swz128(l16, kk));
        short8 b1 = lds8(sKm + swz128(16 + l16, kk));
        short8 b2 = lds8(sKm + swz128(32 + l16, kk));
        short8 b3 = lds8(sKm + swz128(48 + l16, kk));
        sc[0] = mfma16(a, b0, sc[0]);
        sc[1] = mfma16(a, b1, sc[1]);
        sc[2] = mfma16(a, b2, sc[2]);
        sc[3] = mfma16(a, b3, sc[3]);
      }
#pragma unroll
      for (int r = 0; r < 4; ++r) {
        float m = fmaxf(fmaxf(sc[0][r], sc[1][r]), fmaxf(sc[2][r], sc[3][r]));
        m = fmaxf(m, __shfl_xor(m, 1));
        m = fmaxf(m, __shfl_xor(m, 2));
        m = fmaxf(m, __shfl_xor(m, 4));
        m = fmaxf(m, __shfl_xor(m, 8));
        float e0 = __expf(sc[0][r] - m), e1 = __expf(sc[1][r] - m);
        float e2 = __expf(sc[2][r] - m), e3 = __expf(sc[3][r] - m);
        float s = e0 + e1 + e2 + e3;
        s += __shfl_xor(s, 1);
        s += __shfl_xor(s, 2);
        s += __shfl_xor(s, 4);
        s += __shfl_xor(s, 8);
        float inv = 1.0f / s;
        int row = mt4 * 16 + lg * 4 + r;
        int cb = hp * 128 + hh * 64;
        sOall[swzT(row, cb + l16)]      = f2bf(e0 * inv);   // P over Q (own rows/cols)
        sOall[swzT(row, cb + 16 + l16)] = f2bf(e1 * inv);
        sOall[swzT(row, cb + 32 + l16)] = f2bf(e2 * inv);
        sOall[swzT(row, cb + 48 + l16)] = f2bf(e3 * inv);
      }
      // PV: O = P @ V (same wave owns its P rows)
      f32x4 ov[4] = {};
#pragma unroll
      for (int ks = 0; ks < 2; ++ks) {
        int kbase = ks * 32 + lg * 8;
        short8 a  = lds8(sOall + swzT(mt4 * 16 + l16, hp * 128 + hh * 64 + kbase));
        short8 b0 = lds8(sVtm + swzV(hh * 64 + l16, kbase));
        short8 b1 = lds8(sVtm + swzV(hh * 64 + 16 + l16, kbase));
        short8 b2 = lds8(sVtm + swzV(hh * 64 + 32 + l16, kbase));
        short8 b3 = lds8(sVtm + swzV(hh * 64 + 48 + l16, kbase));
        ov[0] = mfma16(a, b0, ov[0]);
        ov[1] = mfma16(a, b1, ov[1]);
        ov[2] = mfma16(a, b2, ov[2]);
        ov[3] = mfma16(a, b3, ov[3]);
      }
#pragma unroll
      for (int r = 0; r < 4; ++r) {
        int row = mt4 * 16 + lg * 4 + r;
        int cb = hp * 128 + hh * 64;
        sOall[swzT(row, cb + l16)]      = f2bf(ov[0][r]);
        sOall[swzT(row, cb + 16 + l16)] = f2bf(ov[1][r]);
        sOall[swzT(row, cb + 32 + l16)] = f2bf(ov[2][r]);
        sOall[swzT(row, cb + 48 + l16)] = f2bf(ov[3][r]);
      }
    }
    __syncthreads();  // next Phase A rewrites sKm/sVtm; O slice persists
  }

  // ---- Phase OP: Y = O @ Wo (K=512; wave: 64 rows x 32 cols) ----
  f32x4 Yacc[4][2] = {};
  {
    const unsigned short* wo0 = WoT + (size_t)(nc0 + l16) * 512;
    const unsigned short* wo1 = WoT + (size_t)(nc0 + 16 + l16) * 512;
    short8 wb[2][2];
#pragma unroll
    for (int p = 0; p < 2; ++p) {
      int ko = p * 32 + lg * 8;
      wb[p][0] = *(const short8*)(wo0 + ko);
      wb[p][1] = *(const short8*)(wo1 + ko);
    }
#pragma unroll
    for (int ks = 0; ks < 16; ++ks) {
      int ko = ks * 32 + lg * 8;
      short8 w0 = wb[ks & 1][0], w1 = wb[ks & 1][1];
      if (ks < 14) {
        int ko2 = (ks + 2) * 32 + lg * 8;
        wb[ks & 1][0] = *(const short8*)(wo0 + ko2);
        wb[ks & 1][1] = *(const short8*)(wo1 + ko2);
      }
      short8 a0 = lds8(sOall + swzT(l16, ko));
      short8 a1 = lds8(sOall + swzT(16 + l16, ko));
      short8 a2 = lds8(sOall + swzT(32 + l16, ko));
      short8 a3 = lds8(sOall + swzT(48 + l16, ko));
      Yacc[0][0] = mfma16(a0, w0, Yacc[0][0]);
      Yacc[1][0] = mfma16(a1, w0, Yacc[1][0]);
      Yacc[2][0] = mfma16(a2, w0, Yacc[2][0]);
      Yacc[3][0] = mfma16(a3, w0, Yacc[3][0]);
      Yacc[0][1] = mfma16(a0, w1, Yacc[0][1]);
      Yacc[1][1] = mfma16(a1, w1, Yacc[1][1]);
      Yacc[2][1] = mfma16(a2, w1, Yacc[2][1]);
      Yacc[3][1] = mfma16(a3, w1, Yacc[3][1]);
    }
  }

  // ---- Residual 1 + LayerNorm 1 -> x1 (overwrites sTm) ----
  {
#pragma unroll
    for (int nt = 0; nt < 2; ++nt) {
      int col = nc0 + nt * 16 + l16;
      float bv = bo[col];
#pragma unroll
      for (int mt = 0; mt < 4; ++mt) {
        int row0 = mt * 16 + lg * 4;
#pragma unroll
        for (int r = 0; r < 4; ++r)
          Yacc[mt][nt][r] += bv + bf2f(sTm[swzT(row0 + r, col)]);
      }
    }
#pragma unroll
    for (int mt = 0; mt < 4; ++mt) {
#pragma unroll
      for (int r = 0; r < 4; ++r) {
        float s = Yacc[mt][0][r] + Yacc[mt][1][r];
        float q = Yacc[mt][0][r] * Yacc[mt][0][r] + Yacc[mt][1][r] * Yacc[mt][1][r];
        s += __shfl_xor(s, 1); s += __shfl_xor(s, 2);
        s += __shfl_xor(s, 4); s += __shfl_xor(s, 8);
        q += __shfl_xor(q, 1); q += __shfl_xor(q, 2);
        q += __shfl_xor(q, 4); q += __shfl_xor(q, 8);
        if (l16 == 0) {
          sSum[wvid * 64 + mt * 16 + lg * 4 + r] = s;
          sSq[wvid * 64 + mt * 16 + lg * 4 + r] = q;
        }
      }
    }
    __syncthreads();
    if (tid < 64) {
      float s = 0.f, q = 0.f;
#pragma unroll
      for (int w = 0; w < 16; ++w) { s += sSum[w * 64 + tid]; q += sSq[w * 64 + tid]; }
      float mean = s * (1.0f / 512.0f);
      float var = q * (1.0f / 512.0f) - mean * mean;
      sMean[tid] = mean;
      sRstd[tid] = rsqrtf(var + 1e-5f);
    }
    __syncthreads();
#pragma unroll
    for (int nt = 0; nt < 2; ++nt) {
      int col = nc0 + nt * 16 + l16;
      float gv = g1[col], bv = beta1[col];
#pragma unroll
      for (int mt = 0; mt < 4; ++mt) {
        int row0 = mt * 16 + lg * 4;
#pragma unroll
        for (int r = 0; r < 4; ++r) {
          float xv = (Yacc[mt][nt][r] - sMean[row0 + r]) * sRstd[row0 + r] * gv + bv;
          sTm[swzT(row0 + r, col)] = f2bf(xv);
        }
      }
    }
  }
  __syncthreads();

  // ---- FFN: 4 hidden chunks of 128 ----
  f32x4 Facc[4][2] = {};
  for (int hc = 0; hc < 4; ++hc) {
    // F1: u = relu(x1 @ W1 chunk) (wave: 32 rows x 16 hidden cols)
    {
      const int hcol = hc * 128 + c2;
      const unsigned short* w1p = W1T + (size_t)hcol * 512;
      f32x4 u[2] = {};
      short8 wbuf[2];
      wbuf[0] = *(const short8*)(w1p + lg * 8);
      wbuf[1] = *(const short8*)(w1p + 32 + lg * 8);
#pragma unroll
      for (int ks = 0; ks < 16; ++ks) {
        int ko = ks * 32 + lg * 8;
        short8 cw = wbuf[ks & 1];
        if (ks < 14)
          wbuf[ks & 1] = *(const short8*)(w1p + (ks + 2) * 32 + lg * 8);
        short8 a0 = lds8(sTm + swzT(rt2 * 32 + l16, ko));
        short8 a1 = lds8(sTm + swzT(rt2 * 32 + 16 + l16, ko));
        u[0] = mfma16(a0, cw, u[0]);
        u[1] = mfma16(a1, cw, u[1]);
      }
      float bv = bf1[hcol];
#pragma unroll
      for (int mt2 = 0; mt2 < 2; ++mt2) {
        int tok0 = rt2 * 32 + mt2 * 16 + lg * 4;
#pragma unroll
        for (int r = 0; r < 4; ++r)
          sKm[swz128(tok0 + r, c2)] = f2bf(fmaxf(u[mt2][r] + bv, 0.0f));
      }
    }
    __syncthreads();
    // F2: Facc += u @ W2[hc*128.., nc0..+32]
    {
      const unsigned short* w2p0 = W2T + (size_t)(nc0 + l16) * 512 + hc * 128;
      const unsigned short* w2p1 = W2T + (size_t)(nc0 + 16 + l16) * 512 + hc * 128;
      short8 wb[2][2];
#pragma unroll
      for (int p = 0; p < 2; ++p) {
        int ko = p * 32 + lg * 8;
        wb[p][0] = *(const short8*)(w2p0 + ko);
        wb[p][1] = *(const short8*)(w2p1 + ko);
      }
#pragma unroll
      for (int ks = 0; ks < 4; ++ks) {
        int ko = ks * 32 + lg * 8;
        short8 w0 = wb[ks & 1][0], w1 = wb[ks & 1][1];
        if (ks < 2) {
          int ko2 = (ks + 2) * 32 + lg * 8;
          wb[ks & 1][0] = *(const short8*)(w2p0 + ko2);
          wb[ks & 1][1] = *(const short8*)(w2p1 + ko2);
        }
        short8 a0 = lds8(sKm + swz128(l16, ko));
        short8 a1 = lds8(sKm + swz128(16 + l16, ko));
        short8 a2 = lds8(sKm + swz128(32 + l16, ko));
        short8 a3 = lds8(sKm + swz128(48 + l16, ko));
        Facc[0][0] = mfma16(a0, w0, Facc[0][0]);
        Facc[1][0] = mfma16(a1, w0, Facc[1][0]);
        Facc[2][0] = mfma16(a2, w0, Facc[2][0]);
        Facc[3][0] = mfma16(a3, w0, Facc[3][0]);
        Facc[0][1] = mfma16(a0, w1, Facc[0][1]);
        Facc[1][1] = mfma16(a1, w1, Facc[1][1]);
        Facc[2][1] = mfma16(a2, w1, Facc[2][1]);
        Facc[3][1] = mfma16(a3, w1, Facc[3][1]);
      }
    }
    __syncthreads();  // sKm reused next chunk
  }

  // ---- Residual 2 + LayerNorm 2 -> output ----
  {
#pragma unroll
    for (int nt = 0; nt < 2; ++nt) {
      int col = nc0 + nt * 16 + l16;
      float bv = bf2[col];
#pragma unroll
      for (int mt = 0; mt < 4; ++mt) {
        int row0 = mt * 16 + lg * 4;
#pragma unroll
        for (int r = 0; r < 4; ++r)
          Facc[mt][nt][r] += bv + bf2f(sTm[swzT(row0 + r, col)]);
      }
    }
#pragma unroll
    for (int mt = 0; mt < 4; ++mt) {
#pragma unroll
      for (int r = 0; r < 4; ++r) {
        float s = Facc[mt][0][r] + Facc[mt][1][r];
        float q = Facc[mt][0][r] * Facc[mt][0][r] + Facc[mt][1][r] * Facc[mt][1][r];
        s += __shfl_xor(s, 1); s += __shfl_xor(s, 2);
        s += __shfl_xor(s, 4); s += __shfl_xor(s, 8);
        q += __shfl_xor(q, 1); q += __shfl_xor(q, 2);
        q += __shfl_xor(q, 4); q += __shfl_xor(q, 8);
        if (l16 == 0) {
          sSum[wvid * 64 + mt * 16 + lg * 4 + r] = s;
          sSq[wvid * 64 + mt * 16 + lg * 4 + r] = q;
        }
      }
    }
    __syncthreads();
    if (tid < 64) {
      float s = 0.f, q = 0.f;
#pragma unroll
      for (int w = 0; w < 16; ++w) { s += sSum[w * 64 + tid]; q += sSq[w * 64 + tid]; }
      float mean = s * (1.0f / 512.0f);
      float var = q * (1.0f / 512.0f) - mean * mean;
      sMean[tid] = mean;
      sRstd[tid] = rsqrtf(var + 1e-5f);
    }
    __syncthreads();
#pragma unroll
    for (int nt = 0; nt < 2; ++nt) {
      int col = nc0 + nt * 16 + l16;
      float gv = g2[col], bv = beta2[col];
      float* op = ob + (size_t)col * 9216;
#pragma unroll
      for (int mt = 0; mt < 4; ++mt) {
        int t0 = mt * 16 + lg * 4;
        float4 o4;
        o4.x = (Facc[mt][nt][0] - sMean[t0 + 0]) * sRstd[t0 + 0] * gv + bv;
        o4.y = (Facc[mt][nt][1] - sMean[t0 + 1]) * sRstd[t0 + 1] * gv + bv;
        o4.z = (Facc[mt][nt][2] - sMean[t0 + 2]) * sRstd[t0 + 2] * gv + bv;
        o4.w = (Facc[mt][nt][3] - sMean[t0 + 3]) * sRstd[t0 + 3] * gv + bv;
        *reinterpret_cast<float4*>(op + (t0 >> 3) * 96 + (t0 & 7)) = o4;
      }
    }
  }
}

extern "C" void kernel_launch(void* const* d_in, const int* in_sizes, int n_in,
                              void* d_out, int out_size, void* d_ws, size_t ws_size,
                              hipStream_t stream) {
  const float* x     = (const float*)d_in[0];
  const float* Wqkv  = (const float*)d_in[1];
  const float* bqkv  = (const float*)d_in[2];
  const float* Wo    = (const float*)d_in[3];
  const float* bo    = (const float*)d_in[4];
  const float* g1    = (const float*)d_in[5];
  const float* beta1 = (const float*)d_in[6];
  const float* W1    = (const float*)d_in[7];
  const float* bf1   = (const float*)d_in[8];
  const float* W2    = (const float*)d_in[9];
  const float* bf2   = (const float*)d_in[10];
  const float* g2    = (const float*)d_in[11];
  const float* beta2 = (const float*)d_in[12];
  float* out = (float*)d_out;

  unsigned short* ws = (unsigned short*)d_ws;
  unsigned short* WqkvT = ws;                          // 1536*512
  unsigned short* WoT   = ws + (size_t)1536 * 512;
  unsigned short* W1T   = WoT + (size_t)512 * 512;
  unsigned short* W2T   = W1T + (size_t)512 * 512;

  transpose_cvt_kernel<<<dim3(48, 16), 256, 0, stream>>>(Wqkv, WqkvT, 512, 1536);
  transpose_cvt_kernel<<<dim3(16, 16), 256, 0, stream>>>(Wo, WoT, 512, 512);
  transpose_cvt_kernel<<<dim3(16, 16), 256, 0, stream>>>(W1, W1T, 512, 512);
  transpose_cvt_kernel<<<dim3(16, 16), 256, 0, stream>>>(W2, W2T, 512, 512);

  (void)hipFuncSetAttribute((const void*)swin_fused,
                            hipFuncAttributeMaxDynamicSharedMemorySize, SMEM_BYTES);
  swin_fused<<<NWIN, 1024, SMEM_BYTES, stream>>>(x, WqkvT, bqkv, WoT, bo, g1, beta1,
                                                 W1T, bf1, W2T, bf2, g2, beta2, out);
}

// Round 9
// 1587.784 us; speedup vs baseline: 1.2987x; 1.2139x over previous
//
#include <hip/hip_runtime.h>

typedef short short8 __attribute__((ext_vector_type(8)));
typedef float f32x4 __attribute__((ext_vector_type(4)));

#define NWIN 2304
#define SMEM_BYTES 81920

static __device__ __forceinline__ unsigned short f2bf(float f) {
  unsigned int u = __float_as_uint(f);
  u += 0x7FFFu + ((u >> 16) & 1u);   // RNE
  return (unsigned short)(u >> 16);
}
static __device__ __forceinline__ float bf2f(unsigned short s) {
  return __uint_as_float(((unsigned int)s) << 16);
}
static __device__ __forceinline__ f32x4 mfma16(short8 a, short8 b, f32x4 c) {
  return __builtin_amdgcn_mfma_f32_16x16x32_bf16(a, b, c, 0, 0, 0);
}
static __device__ __forceinline__ short8 lds8(const unsigned short* p) {
  return *reinterpret_cast<const short8*>(p);
}
// XOR swizzles: 16B granule, spread by low row bits
static __device__ __forceinline__ int swzH(int r, int c) {   // [64][256]
  return r * 256 + ((((c >> 3) ^ (r & 7)) << 3) | (c & 7));
}
static __device__ __forceinline__ int swzT(int r, int c) {   // [64][512]
  return r * 512 + ((((c >> 3) ^ (r & 7)) << 3) | (c & 7));
}
static __device__ __forceinline__ int swz128(int r, int c) { // [64][128]
  return r * 128 + ((((c >> 3) ^ (r & 7)) << 3) | (c & 7));
}
static __device__ __forceinline__ int swzV(int r, int c) {   // [128][64]
  return r * 64 + ((((c >> 3) ^ (r & 7)) << 3) | (c & 7));
}

// ---- weight prep: in[K][N] f32  ->  out[N][K] bf16 ----
__global__ void transpose_cvt_kernel(const float* __restrict__ in,
                                     unsigned short* __restrict__ out,
                                     int K, int N) {
  __shared__ float tile[32][33];
  int bn = blockIdx.x * 32, bk = blockIdx.y * 32;
  int tx = threadIdx.x & 31, ty = threadIdx.x >> 5;  // 256 thr: 32 x 8
#pragma unroll
  for (int r = 0; r < 32; r += 8)
    tile[ty + r][tx] = in[(size_t)(bk + ty + r) * N + bn + tx];
  __syncthreads();
#pragma unroll
  for (int r = 0; r < 32; r += 8)
    out[(size_t)(bn + ty + r) * K + bk + tx] = f2bf(tile[tx][ty + r]);
}

__global__ __launch_bounds__(512, 2)
void swin_fused(const float* __restrict__ x,
                const unsigned short* __restrict__ WqkvT,  // [1536][512] bf16
                const float* __restrict__ bqkv,
                const unsigned short* __restrict__ WoT,    // [512][512]
                const float* __restrict__ bo,
                const float* __restrict__ g1, const float* __restrict__ beta1,
                const unsigned short* __restrict__ W1T,    // [512][512]
                const float* __restrict__ bf1,
                const unsigned short* __restrict__ W2T,    // [512][512]
                const float* __restrict__ bf2,
                const float* __restrict__ g2, const float* __restrict__ beta2,
                float* __restrict__ out) {
  extern __shared__ unsigned char smem[];
  unsigned short* sTh = (unsigned short*)smem;             // [64][256] x half (attn)
  unsigned short* sQ  = (unsigned short*)(smem + 32768);   // [64][128] q->P->O per hp
  unsigned short* sK  = (unsigned short*)(smem + 49152);   // [64][128] k per hp
  unsigned short* sVt = (unsigned short*)(smem + 65536);   // [128][64] V^T per hp
  unsigned short* sX1 = (unsigned short*)smem;             // [64][512] x1 (FFN; overlays sTh+sQ+sK)
  unsigned short* sU  = sVt;                               // [64][128] hidden chunk (FFN)
  float* sSum  = (float*)(smem + 65536);                   // overlay sVt (LN phases only)
  float* sSq   = (float*)(smem + 67584);
  float* sMean = (float*)(smem + 69632);
  float* sRstd = (float*)(smem + 69888);

  const int tid = threadIdx.x;
  const int wvid = tid >> 6, lane = tid & 63;
  const int l16 = lane & 15, lg = lane >> 4;

  // XCD swizzle (bijective: 2304 % 8 == 0)
  const int wid = (blockIdx.x & 7) * 288 + (blockIdx.x >> 3);
  const int b = wid / 144, rem = wid % 144;
  const int h0 = (rem / 12) * 8, w0 = (rem % 12) * 8;
  const float* xb = x + (size_t)b * 512 * 9216 + (size_t)h0 * 96 + w0;
  float* ob = out + (size_t)b * 512 * 9216 + (size_t)h0 * 96 + w0;

  // wave roles
  const int c2 = wvid * 16 + l16;   // qkv col within 128 (A) / hidden col (F1)
  const int hh = wvid >> 2;         // head within pair (S / PV)
  const int mt4 = wvid & 3;         // 16-row tile (S / PV)
  const int ycol0 = wvid * 64;      // wave's 64 C-cols (OP / LN / F2)

  f32x4 Yacc[4][4] = {};  // o-proj accumulator [row tile][col tile]

  for (int hp = 0; hp < 4; ++hp) {   // head pairs
    // ---- Phase A: q,k,v (wave: 64 rows x 16 cols x 3 mats; K in 2 staged halves) ----
    f32x4 acc[3][4] = {};
    const unsigned short* bq0 = WqkvT + (size_t)(hp * 128 + c2) * 512;
    for (int kh = 0; kh < 2; ++kh) {
      // stage x half [64][kh*256..+256] -> sTh
#pragma unroll
      for (int it = 0; it < 8; ++it) {
        int gid = it * 512 + tid;               // gid = c*16 + hr*2 + wq
        int c = gid >> 4, hr = (gid >> 1) & 7, wq = gid & 1;
        float4 v = *reinterpret_cast<const float4*>(
            xb + (size_t)(kh * 256 + c) * 9216 + hr * 96 + wq * 4);
        int tok = hr * 8 + wq * 4;
        sTh[swzH(tok + 0, c)] = f2bf(v.x);
        sTh[swzH(tok + 1, c)] = f2bf(v.y);
        sTh[swzH(tok + 2, c)] = f2bf(v.z);
        sTh[swzH(tok + 3, c)] = f2bf(v.w);
      }
      __syncthreads();
      const unsigned short* bq = bq0 + kh * 256;
      const unsigned short* bk = bq + (size_t)512 * 512;
      const unsigned short* bv = bq + (size_t)1024 * 512;
      short8 qw[2], kw[2], vw[2];
#pragma unroll
      for (int p = 0; p < 2; ++p) {
        int ko = p * 32 + lg * 8;
        qw[p] = *(const short8*)(bq + ko);
        kw[p] = *(const short8*)(bk + ko);
        vw[p] = *(const short8*)(bv + ko);
      }
#pragma unroll
      for (int ks = 0; ks < 8; ++ks) {
        const int ko = ks * 32 + lg * 8;
        short8 cq = qw[ks & 1], ck = kw[ks & 1], cv = vw[ks & 1];
        if (ks < 6) {
          int k2 = (ks + 2) * 32 + lg * 8;
          qw[ks & 1] = *(const short8*)(bq + k2);
          kw[ks & 1] = *(const short8*)(bk + k2);
          vw[ks & 1] = *(const short8*)(bv + k2);
        }
        short8 a0 = lds8(sTh + swzH(l16, ko));
        short8 a1 = lds8(sTh + swzH(16 + l16, ko));
        short8 a2 = lds8(sTh + swzH(32 + l16, ko));
        short8 a3 = lds8(sTh + swzH(48 + l16, ko));
        acc[0][0] = mfma16(a0, cq, acc[0][0]);
        acc[0][1] = mfma16(a1, cq, acc[0][1]);
        acc[0][2] = mfma16(a2, cq, acc[0][2]);
        acc[0][3] = mfma16(a3, cq, acc[0][3]);
        acc[1][0] = mfma16(a0, ck, acc[1][0]);
        acc[1][1] = mfma16(a1, ck, acc[1][1]);
        acc[1][2] = mfma16(a2, ck, acc[1][2]);
        acc[1][3] = mfma16(a3, ck, acc[1][3]);
        acc[2][0] = mfma16(a0, cv, acc[2][0]);
        acc[2][1] = mfma16(a1, cv, acc[2][1]);
        acc[2][2] = mfma16(a2, cv, acc[2][2]);
        acc[2][3] = mfma16(a3, cv, acc[2][3]);
      }
      __syncthreads();  // before next stage overwrites sTh
    }
    {
      const float bqv = bqkv[hp * 128 + c2];
      const float bkv = bqkv[512 + hp * 128 + c2];
      const float bvv = bqkv[1024 + hp * 128 + c2];
#pragma unroll
      for (int mt = 0; mt < 4; ++mt) {
        int tok0 = mt * 16 + lg * 4;
#pragma unroll
        for (int r = 0; r < 4; ++r) {
          sQ[swz128(tok0 + r, c2)] = f2bf((acc[0][mt][r] + bqv) * 0.125f);
          sK[swz128(tok0 + r, c2)] = f2bf(acc[1][mt][r] + bkv);
        }
        ushort4 pk;
        pk.x = f2bf(acc[2][mt][0] + bvv);
        pk.y = f2bf(acc[2][mt][1] + bvv);
        pk.z = f2bf(acc[2][mt][2] + bvv);
        pk.w = f2bf(acc[2][mt][3] + bvv);
        *reinterpret_cast<ushort4*>(sVt + swzV(c2, tok0)) = pk;
      }
    }
    __syncthreads();

    // ---- Phase S: scores + wave-local softmax (head hh, rows mt4*16..) ----
    {
      f32x4 sc[4] = {};
#pragma unroll
      for (int ks = 0; ks < 2; ++ks) {
        int kb = hh * 64 + ks * 32 + lg * 8;
        short8 a  = lds8(sQ + swz128(mt4 * 16 + l16, kb));
        short8 b0 = lds8(sK + swz128(l16, kb));
        short8 b1 = lds8(sK + swz128(16 + l16, kb));
        short8 b2 = lds8(sK + swz128(32 + l16, kb));
        short8 b3 = lds8(sK + swz128(48 + l16, kb));
        sc[0] = mfma16(a, b0, sc[0]);
        sc[1] = mfma16(a, b1, sc[1]);
        sc[2] = mfma16(a, b2, sc[2]);
        sc[3] = mfma16(a, b3, sc[3]);
      }
#pragma unroll
      for (int r = 0; r < 4; ++r) {
        float m = fmaxf(fmaxf(sc[0][r], sc[1][r]), fmaxf(sc[2][r], sc[3][r]));
        m = fmaxf(m, __shfl_xor(m, 1));
        m = fmaxf(m, __shfl_xor(m, 2));
        m = fmaxf(m, __shfl_xor(m, 4));
        m = fmaxf(m, __shfl_xor(m, 8));
        float e0 = __expf(sc[0][r] - m), e1 = __expf(sc[1][r] - m);
        float e2 = __expf(sc[2][r] - m), e3 = __expf(sc[3][r] - m);
        float s = e0 + e1 + e2 + e3;
        s += __shfl_xor(s, 1);
        s += __shfl_xor(s, 2);
        s += __shfl_xor(s, 4);
        s += __shfl_xor(s, 8);
        float inv = 1.0f / s;
        int row = mt4 * 16 + lg * 4 + r;
        sQ[swz128(row, hh * 64 + l16)]      = f2bf(e0 * inv);  // P over q (own rows)
        sQ[swz128(row, hh * 64 + 16 + l16)] = f2bf(e1 * inv);
        sQ[swz128(row, hh * 64 + 32 + l16)] = f2bf(e2 * inv);
        sQ[swz128(row, hh * 64 + 48 + l16)] = f2bf(e3 * inv);
      }
    }
    // no barrier: P produced and consumed by same wave

    // ---- Phase PV: O = P @ V (write O over P, own rows) ----
    {
      f32x4 ov[4] = {};
#pragma unroll
      for (int ks = 0; ks < 2; ++ks) {
        int kb = ks * 32 + lg * 8;
        short8 a  = lds8(sQ + swz128(mt4 * 16 + l16, hh * 64 + kb));
        short8 b0 = lds8(sVt + swzV(hh * 64 + l16, kb));
        short8 b1 = lds8(sVt + swzV(hh * 64 + 16 + l16, kb));
        short8 b2 = lds8(sVt + swzV(hh * 64 + 32 + l16, kb));
        short8 b3 = lds8(sVt + swzV(hh * 64 + 48 + l16, kb));
        ov[0] = mfma16(a, b0, ov[0]);
        ov[1] = mfma16(a, b1, ov[1]);
        ov[2] = mfma16(a, b2, ov[2]);
        ov[3] = mfma16(a, b3, ov[3]);
      }
#pragma unroll
      for (int r = 0; r < 4; ++r) {
        int row = mt4 * 16 + lg * 4 + r;
        sQ[swz128(row, hh * 64 + l16)]      = f2bf(ov[0][r]);
        sQ[swz128(row, hh * 64 + 16 + l16)] = f2bf(ov[1][r]);
        sQ[swz128(row, hh * 64 + 32 + l16)] = f2bf(ov[2][r]);
        sQ[swz128(row, hh * 64 + 48 + l16)] = f2bf(ov[3][r]);
      }
    }
    __syncthreads();

    // ---- Phase OP: Yacc += O @ Wo[hp*128.., ycol0..+64] ----
    {
      const unsigned short* wo[4];
#pragma unroll
      for (int nt = 0; nt < 4; ++nt)
        wo[nt] = WoT + (size_t)(ycol0 + nt * 16 + l16) * 512 + hp * 128;
      short8 wb[2][4];
#pragma unroll
      for (int p = 0; p < 2; ++p)
#pragma unroll
        for (int nt = 0; nt < 4; ++nt)
          wb[p][nt] = *(const short8*)(wo[nt] + p * 32 + lg * 8);
#pragma unroll
      for (int ks = 0; ks < 4; ++ks) {
        int ko = ks * 32 + lg * 8;
        short8 a0 = lds8(sQ + swz128(l16, ko));
        short8 a1 = lds8(sQ + swz128(16 + l16, ko));
        short8 a2 = lds8(sQ + swz128(32 + l16, ko));
        short8 a3 = lds8(sQ + swz128(48 + l16, ko));
#pragma unroll
        for (int nt = 0; nt < 4; ++nt) {
          short8 w = wb[ks & 1][nt];
          if (ks < 2) wb[ks & 1][nt] = *(const short8*)(wo[nt] + (ks + 2) * 32 + lg * 8);
          Yacc[0][nt] = mfma16(a0, w, Yacc[0][nt]);
          Yacc[1][nt] = mfma16(a1, w, Yacc[1][nt]);
          Yacc[2][nt] = mfma16(a2, w, Yacc[2][nt]);
          Yacc[3][nt] = mfma16(a3, w, Yacc[3][nt]);
        }
      }
    }
    __syncthreads();  // next hp rewrites sTh/sQ/sK/sVt
  }

  // ---- Residual 1 (x from global, L2-hot) + LayerNorm 1 -> x1 in sX1 ----
  {
#pragma unroll
    for (int nt = 0; nt < 4; ++nt) {
      int col = ycol0 + nt * 16 + l16;
      float bv = bo[col];
      const float* xc = xb + (size_t)col * 9216;
#pragma unroll
      for (int mt = 0; mt < 4; ++mt) {
        int row0 = mt * 16 + lg * 4;
        float4 xv = *reinterpret_cast<const float4*>(xc + (row0 >> 3) * 96 + (row0 & 7));
        Yacc[mt][nt][0] += bv + xv.x;
        Yacc[mt][nt][1] += bv + xv.y;
        Yacc[mt][nt][2] += bv + xv.z;
        Yacc[mt][nt][3] += bv + xv.w;
      }
    }
#pragma unroll
    for (int mt = 0; mt < 4; ++mt) {
#pragma unroll
      for (int r = 0; r < 4; ++r) {
        float s = Yacc[mt][0][r] + Yacc[mt][1][r] + Yacc[mt][2][r] + Yacc[mt][3][r];
        float q = Yacc[mt][0][r] * Yacc[mt][0][r] + Yacc[mt][1][r] * Yacc[mt][1][r] +
                  Yacc[mt][2][r] * Yacc[mt][2][r] + Yacc[mt][3][r] * Yacc[mt][3][r];
        s += __shfl_xor(s, 1); s += __shfl_xor(s, 2);
        s += __shfl_xor(s, 4); s += __shfl_xor(s, 8);
        q += __shfl_xor(q, 1); q += __shfl_xor(q, 2);
        q += __shfl_xor(q, 4); q += __shfl_xor(q, 8);
        if (l16 == 0) {
          sSum[wvid * 64 + mt * 16 + lg * 4 + r] = s;
          sSq[wvid * 64 + mt * 16 + lg * 4 + r] = q;
        }
      }
    }
    __syncthreads();
    if (tid < 64) {
      float s = 0.f, q = 0.f;
#pragma unroll
      for (int w = 0; w < 8; ++w) { s += sSum[w * 64 + tid]; q += sSq[w * 64 + tid]; }
      float mean = s * (1.0f / 512.0f);
      float var = q * (1.0f / 512.0f) - mean * mean;
      sMean[tid] = mean;
      sRstd[tid] = rsqrtf(var + 1e-5f);
    }
    __syncthreads();
#pragma unroll
    for (int nt = 0; nt < 4; ++nt) {
      int col = ycol0 + nt * 16 + l16;
      float gv = g1[col], bv = beta1[col];
#pragma unroll
      for (int mt = 0; mt < 4; ++mt) {
        int row0 = mt * 16 + lg * 4;
#pragma unroll
        for (int r = 0; r < 4; ++r) {
          float xv = (Yacc[mt][nt][r] - sMean[row0 + r]) * sRstd[row0 + r] * gv + bv;
          sX1[swzT(row0 + r, col)] = f2bf(xv);
        }
      }
    }
  }
  __syncthreads();

  // ---- FFN: 4 hidden chunks of 128 (x1 from sX1; U in sU=sVt) ----
  f32x4 Facc[4][4] = {};
  for (int hc = 0; hc < 4; ++hc) {
    // F1: u = relu(x1 @ W1 chunk) (wave: 64 rows x 16 hidden cols)
    {
      const int hcol = hc * 128 + c2;
      const unsigned short* w1p = W1T + (size_t)hcol * 512;
      f32x4 u[4] = {};
      short8 wbuf[2];
      wbuf[0] = *(const short8*)(w1p + lg * 8);
      wbuf[1] = *(const short8*)(w1p + 32 + lg * 8);
#pragma unroll
      for (int ks = 0; ks < 16; ++ks) {
        int ko = ks * 32 + lg * 8;
        short8 cw = wbuf[ks & 1];
        if (ks < 14)
          wbuf[ks & 1] = *(const short8*)(w1p + (ks + 2) * 32 + lg * 8);
        short8 a0 = lds8(sX1 + swzT(l16, ko));
        short8 a1 = lds8(sX1 + swzT(16 + l16, ko));
        short8 a2 = lds8(sX1 + swzT(32 + l16, ko));
        short8 a3 = lds8(sX1 + swzT(48 + l16, ko));
        u[0] = mfma16(a0, cw, u[0]);
        u[1] = mfma16(a1, cw, u[1]);
        u[2] = mfma16(a2, cw, u[2]);
        u[3] = mfma16(a3, cw, u[3]);
      }
      float bv = bf1[hcol];
#pragma unroll
      for (int mt = 0; mt < 4; ++mt) {
        int tok0 = mt * 16 + lg * 4;
#pragma unroll
        for (int r = 0; r < 4; ++r)
          sU[swz128(tok0 + r, c2)] = f2bf(fmaxf(u[mt][r] + bv, 0.0f));
      }
    }
    __syncthreads();
    // F2: Facc += u @ W2[hc*128.., ycol0..+64]
    {
      const unsigned short* w2[4];
#pragma unroll
      for (int nt = 0; nt < 4; ++nt)
        w2[nt] = W2T + (size_t)(ycol0 + nt * 16 + l16) * 512 + hc * 128;
      short8 wb[2][4];
#pragma unroll
      for (int p = 0; p < 2; ++p)
#pragma unroll
        for (int nt = 0; nt < 4; ++nt)
          wb[p][nt] = *(const short8*)(w2[nt] + p * 32 + lg * 8);
#pragma unroll
      for (int ks = 0; ks < 4; ++ks) {
        int ko = ks * 32 + lg * 8;
        short8 a0 = lds8(sU + swz128(l16, ko));
        short8 a1 = lds8(sU + swz128(16 + l16, ko));
        short8 a2 = lds8(sU + swz128(32 + l16, ko));
        short8 a3 = lds8(sU + swz128(48 + l16, ko));
#pragma unroll
        for (int nt = 0; nt < 4; ++nt) {
          short8 w = wb[ks & 1][nt];
          if (ks < 2) wb[ks & 1][nt] = *(const short8*)(w2[nt] + (ks + 2) * 32 + lg * 8);
          Facc[0][nt] = mfma16(a0, w, Facc[0][nt]);
          Facc[1][nt] = mfma16(a1, w, Facc[1][nt]);
          Facc[2][nt] = mfma16(a2, w, Facc[2][nt]);
          Facc[3][nt] = mfma16(a3, w, Facc[3][nt]);
        }
      }
    }
    __syncthreads();  // sU reused next chunk
  }

  // ---- Residual 2 (x1 from sX1) + LayerNorm 2 -> output ----
  {
#pragma unroll
    for (int nt = 0; nt < 4; ++nt) {
      int col = ycol0 + nt * 16 + l16;
      float bv = bf2[col];
#pragma unroll
      for (int mt = 0; mt < 4; ++mt) {
        int row0 = mt * 16 + lg * 4;
#pragma unroll
        for (int r = 0; r < 4; ++r)
          Facc[mt][nt][r] += bv + bf2f(sX1[swzT(row0 + r, col)]);
      }
    }
#pragma unroll
    for (int mt = 0; mt < 4; ++mt) {
#pragma unroll
      for (int r = 0; r < 4; ++r) {
        float s = Facc[mt][0][r] + Facc[mt][1][r] + Facc[mt][2][r] + Facc[mt][3][r];
        float q = Facc[mt][0][r] * Facc[mt][0][r] + Facc[mt][1][r] * Facc[mt][1][r] +
                  Facc[mt][2][r] * Facc[mt][2][r] + Facc[mt][3][r] * Facc[mt][3][r];
        s += __shfl_xor(s, 1); s += __shfl_xor(s, 2);
        s += __shfl_xor(s, 4); s += __shfl_xor(s, 8);
        q += __shfl_xor(q, 1); q += __shfl_xor(q, 2);
        q += __shfl_xor(q, 4); q += __shfl_xor(q, 8);
        if (l16 == 0) {
          sSum[wvid * 64 + mt * 16 + lg * 4 + r] = s;
          sSq[wvid * 64 + mt * 16 + lg * 4 + r] = q;
        }
      }
    }
    __syncthreads();
    if (tid < 64) {
      float s = 0.f, q = 0.f;
#pragma unroll
      for (int w = 0; w < 8; ++w) { s += sSum[w * 64 + tid]; q += sSq[w * 64 + tid]; }
      float mean = s * (1.0f / 512.0f);
      float var = q * (1.0f / 512.0f) - mean * mean;
      sMean[tid] = mean;
      sRstd[tid] = rsqrtf(var + 1e-5f);
    }
    __syncthreads();
#pragma unroll
    for (int nt = 0; nt < 4; ++nt) {
      int col = ycol0 + nt * 16 + l16;
      float gv = g2[col], bv = beta2[col];
      float* op = ob + (size_t)col * 9216;
#pragma unroll
      for (int mt = 0; mt < 4; ++mt) {
        int t0 = mt * 16 + lg * 4;
        float4 o4;
        o4.x = (Facc[mt][nt][0] - sMean[t0 + 0]) * sRstd[t0 + 0] * gv + bv;
        o4.y = (Facc[mt][nt][1] - sMean[t0 + 1]) * sRstd[t0 + 1] * gv + bv;
        o4.z = (Facc[mt][nt][2] - sMean[t0 + 2]) * sRstd[t0 + 2] * gv + bv;
        o4.w = (Facc[mt][nt][3] - sMean[t0 + 3]) * sRstd[t0 + 3] * gv + bv;
        *reinterpret_cast<float4*>(op + (t0 >> 3) * 96 + (t0 & 7)) = o4;
      }
    }
  }
}

extern "C" void kernel_launch(void* const* d_in, const int* in_sizes, int n_in,
                              void* d_out, int out_size, void* d_ws, size_t ws_size,
                              hipStream_t stream) {
  const float* x     = (const float*)d_in[0];
  const float* Wqkv  = (const float*)d_in[1];
  const float* bqkv  = (const float*)d_in[2];
  const float* Wo    = (const float*)d_in[3];
  const float* bo    = (const float*)d_in[4];
  const float* g1    = (const float*)d_in[5];
  const float* beta1 = (const float*)d_in[6];
  const float* W1    = (const float*)d_in[7];
  const float* bf1   = (const float*)d_in[8];
  const float* W2    = (const float*)d_in[9];
  const float* bf2   = (const float*)d_in[10];
  const float* g2    = (const float*)d_in[11];
  const float* beta2 = (const float*)d_in[12];
  float* out = (float*)d_out;

  unsigned short* ws = (unsigned short*)d_ws;
  unsigned short* WqkvT = ws;                          // 1536*512
  unsigned short* WoT   = ws + (size_t)1536 * 512;
  unsigned short* W1T   = WoT + (size_t)512 * 512;
  unsigned short* W2T   = W1T + (size_t)512 * 512;

  transpose_cvt_kernel<<<dim3(48, 16), 256, 0, stream>>>(Wqkv, WqkvT, 512, 1536);
  transpose_cvt_kernel<<<dim3(16, 16), 256, 0, stream>>>(Wo, WoT, 512, 512);
  transpose_cvt_kernel<<<dim3(16, 16), 256, 0, stream>>>(W1, W1T, 512, 512);
  transpose_cvt_kernel<<<dim3(16, 16), 256, 0, stream>>>(W2, W2T, 512, 512);

  (void)hipFuncSetAttribute((const void*)swin_fused,
                            hipFuncAttributeMaxDynamicSharedMemorySize, SMEM_BYTES);
  swin_fused<<<NWIN, 512, SMEM_BYTES, stream>>>(x, WqkvT, bqkv, WoT, bo, g1, beta1,
                                                W1T, bf1, W2T, bf2, g2, beta2, out);
}